// Round 1
// baseline (1681.243 us; speedup 1.0000x reference)
//
#include <hip/hip_runtime.h>
#include <math.h>

#define LN_EPS 1e-5f

// ---- monotonic float<->uint key for atomicMax on floats (0 == -inf identity) ----
__device__ __forceinline__ unsigned fkey(float f) {
    unsigned u = __float_as_uint(f);
    return (u & 0x80000000u) ? ~u : (u | 0x80000000u);
}
__device__ __forceinline__ float fkey_dec(unsigned k) {
    unsigned u = (k & 0x80000000u) ? (k ^ 0x80000000u) : ~k;
    return __uint_as_float(u);
}

// ---------------------------------------------------------------------------
// Kernel 1: fused Q/K/V GEMM.  out = x @ W + b for W in {Wq,Wk,Wv}.
// Block = 256 threads = 4 waves. 32 nodes per block. Each wave owns 8 nodes.
// Thread covers 2 output columns (lane*2, lane*2+1) x 8 nodes.
// ---------------------------------------------------------------------------
__global__ __launch_bounds__(256) void qkv_kernel(
    const float* __restrict__ x,
    const float* __restrict__ Wq, const float* __restrict__ bq,
    const float* __restrict__ Wk, const float* __restrict__ bk,
    const float* __restrict__ Wv, const float* __restrict__ bv,
    float* __restrict__ Q, float* __restrict__ K, float* __restrict__ V,
    int N)
{
    __shared__ float xs[32 * 128];    // 16 KB
    __shared__ float ws[128 * 128];   // 64 KB
    const int tid  = threadIdx.x;
    const int base = blockIdx.x * 32;

    // stage x tile (32 rows x 128 cols) as float4
    for (int i = tid; i < 1024; i += 256) {
        int node = i >> 5;   // 32 float4 per row
        int c4   = i & 31;
        float4 v = (base + node < N)
                 ? ((const float4*)x)[(size_t)(base + node) * 32 + c4]
                 : make_float4(0.f, 0.f, 0.f, 0.f);
        ((float4*)xs)[i] = v;
    }

    const float* Wm[3] = {Wq, Wk, Wv};
    const float* bm[3] = {bq, bk, bv};
    float*       Om[3] = {Q, K, V};

    const int lane = tid & 63;
    const int w    = tid >> 6;   // wave id = node group

#pragma unroll
    for (int m = 0; m < 3; ++m) {
        __syncthreads();   // protect ws from previous readers (and xs at m=0)
        for (int i = tid; i < 4096; i += 256)
            ((float4*)ws)[i] = ((const float4*)Wm[m])[i];
        __syncthreads();

        float2 acc[8];
#pragma unroll
        for (int i = 0; i < 8; ++i) acc[i] = make_float2(0.f, 0.f);

#pragma unroll 4
        for (int k = 0; k < 128; ++k) {
            float2 wv = *(const float2*)&ws[k * 128 + lane * 2];
#pragma unroll
            for (int i = 0; i < 8; ++i) {
                float a = xs[(w * 8 + i) * 128 + k];
                acc[i].x = fmaf(a, wv.x, acc[i].x);
                acc[i].y = fmaf(a, wv.y, acc[i].y);
            }
        }

        float2 bb = *(const float2*)&bm[m][lane * 2];
#pragma unroll
        for (int i = 0; i < 8; ++i) {
            int node = base + w * 8 + i;
            if (node < N) {
                float2 o = make_float2(acc[i].x + bb.x, acc[i].y + bb.y);
                *(float2*)&Om[m][(size_t)node * 128 + lane * 2] = o;
            }
        }
    }
}

// ---------------------------------------------------------------------------
// Kernel 2: per-edge scores + per-head global max.
// 16 lanes per edge; lane j loads float4 j and 16+j of Q[src]/K[dst].
// float4 idx j -> head j>>3 ; float4 idx 16+j -> head 2+(j>>3).
// ---------------------------------------------------------------------------
__global__ __launch_bounds__(256) void score_kernel(
    const float* __restrict__ Q, const float* __restrict__ K,
    const int* __restrict__ ei, int E,
    float* __restrict__ S, unsigned* __restrict__ maxbits)
{
    const float scale = 0.17677669529663687f;   // 1/sqrt(32)
    const int tid = threadIdx.x;
    const int j   = tid & 15;
    const int h0  = j >> 3;   // head of the first float4 (0 or 1)

    float lm0 = -3.0e38f, lm1 = -3.0e38f;   // local maxima: head h0 and head h0+2

    const int egrp    = (blockIdx.x * blockDim.x + tid) >> 4;
    const int estride = (gridDim.x * blockDim.x) >> 4;
    const float4* Q4 = (const float4*)Q;
    const float4* K4 = (const float4*)K;

    for (int e = egrp; e < E; e += estride) {
        int s = ei[e];
        int t = ei[E + e];
        float4 q0 = Q4[(size_t)s * 32 + j];
        float4 q1 = Q4[(size_t)s * 32 + 16 + j];
        float4 k0 = K4[(size_t)t * 32 + j];
        float4 k1 = K4[(size_t)t * 32 + 16 + j];
        float p0 = q0.x * k0.x + q0.y * k0.y + q0.z * k0.z + q0.w * k0.w;
        float p1 = q1.x * k1.x + q1.y * k1.y + q1.z * k1.z + q1.w * k1.w;
#pragma unroll
        for (int m = 1; m <= 4; m <<= 1) {
            p0 += __shfl_xor(p0, m);
            p1 += __shfl_xor(p1, m);
        }
        float s0 = p0 * scale; s0 = (s0 >= 0.f) ? s0 : 0.2f * s0;
        float s1 = p1 * scale; s1 = (s1 >= 0.f) ? s1 : 0.2f * s1;
        lm0 = fmaxf(lm0, s0);
        lm1 = fmaxf(lm1, s1);
        if ((j & 7) == 0) {
            S[(size_t)e * 4 + h0]     = s0;   // head h0
            S[(size_t)e * 4 + 2 + h0] = s1;   // head h0+2
        }
    }

    // block-level per-head max, then one global atomic per head per block
    __shared__ unsigned smax[4];
    if (tid < 4) smax[tid] = 0u;   // 0 is below any encoded float key
    __syncthreads();
    atomicMax(&smax[h0],     fkey(lm0));
    atomicMax(&smax[h0 + 2], fkey(lm1));
    __syncthreads();
    if (tid < 4) atomicMax(&maxbits[tid], smax[tid]);
}

// ---------------------------------------------------------------------------
// Kernel 3: e = exp(s - max); accumulate per-head sums; scatter e * V[src]
// into agg[dst] (UNNORMALIZED — 1/sum applied in the output kernel).
// ---------------------------------------------------------------------------
__global__ __launch_bounds__(256) void scatter_kernel(
    const float* __restrict__ V, const int* __restrict__ ei, int E,
    const float* __restrict__ S, const unsigned* __restrict__ maxbits,
    float* __restrict__ agg, float* __restrict__ sums)
{
    const int tid = threadIdx.x;
    const int j   = tid & 15;
    const int h0  = j >> 3;

    const float gm0 = fkey_dec(maxbits[h0]);
    const float gm1 = fkey_dec(maxbits[h0 + 2]);

    float ls0 = 0.f, ls1 = 0.f;

    const int egrp    = (blockIdx.x * blockDim.x + tid) >> 4;
    const int estride = (gridDim.x * blockDim.x) >> 4;
    const float4* V4 = (const float4*)V;
    const float4* S4 = (const float4*)S;

    for (int e = egrp; e < E; e += estride) {
        int s = ei[e];
        int t = ei[E + e];
        float4 sv = S4[e];   // all 4 head scores (broadcast across the 16 lanes)
        float a0 = __expf((h0 ? sv.y : sv.x) - gm0);   // head h0
        float a1 = __expf((h0 ? sv.w : sv.z) - gm1);   // head h0+2
        if ((j & 7) == 0) { ls0 += a0; ls1 += a1; }

        float4 v0 = V4[(size_t)s * 32 + j];
        float4 v1 = V4[(size_t)s * 32 + 16 + j];
        float* ap = &agg[(size_t)t * 128];
        atomicAdd(ap + 4 * j + 0, a0 * v0.x);
        atomicAdd(ap + 4 * j + 1, a0 * v0.y);
        atomicAdd(ap + 4 * j + 2, a0 * v0.z);
        atomicAdd(ap + 4 * j + 3, a0 * v0.w);
        atomicAdd(ap + 64 + 4 * j + 0, a1 * v1.x);
        atomicAdd(ap + 64 + 4 * j + 1, a1 * v1.y);
        atomicAdd(ap + 64 + 4 * j + 2, a1 * v1.z);
        atomicAdd(ap + 64 + 4 * j + 3, a1 * v1.w);
    }

    __shared__ float ssum[4];
    if (tid < 4) ssum[tid] = 0.f;
    __syncthreads();
    atomicAdd(&ssum[h0],     ls0);
    atomicAdd(&ssum[h0 + 2], ls1);
    __syncthreads();
    if (tid < 4) atomicAdd(&sums[tid], ssum[tid]);
}

// ---------------------------------------------------------------------------
// Kernel 4: h = (agg * inv_sum) @ Wo + bo ; y = x + h ; LayerNorm(y).
// Same GEMM layout as kernel 1; each wave owns 8 node rows so LN reductions
// are pure 64-lane shuffle butterflies.
// ---------------------------------------------------------------------------
__global__ __launch_bounds__(256) void out_kernel(
    const float* __restrict__ x, const float* __restrict__ agg,
    const float* __restrict__ Wo, const float* __restrict__ bo,
    const float* __restrict__ gamma, const float* __restrict__ beta,
    const float* __restrict__ sums, float* __restrict__ out, int N)
{
    __shared__ float as[32 * 128];    // scaled agg tile, 16 KB
    __shared__ float ws[128 * 128];   // Wo, 64 KB
    const int tid  = threadIdx.x;
    const int base = blockIdx.x * 32;

    const float inv0 = 1.f / sums[0];
    const float inv1 = 1.f / sums[1];
    const float inv2 = 1.f / sums[2];
    const float inv3 = 1.f / sums[3];

    // stage scaled agg tile (scalar, coalesced: consecutive tid -> consecutive k)
    for (int i = tid; i < 4096; i += 256) {
        int node = i >> 7, k = i & 127;
        float iv = (k < 64) ? ((k < 32) ? inv0 : inv1)
                            : ((k < 96) ? inv2 : inv3);
        as[i] = (base + node < N) ? agg[(size_t)(base + node) * 128 + k] * iv : 0.f;
    }
    for (int i = tid; i < 4096; i += 256)
        ((float4*)ws)[i] = ((const float4*)Wo)[i];
    __syncthreads();

    const int lane = tid & 63;
    const int w    = tid >> 6;

    float2 acc[8];
#pragma unroll
    for (int i = 0; i < 8; ++i) acc[i] = make_float2(0.f, 0.f);

#pragma unroll 4
    for (int k = 0; k < 128; ++k) {
        float2 wv = *(const float2*)&ws[k * 128 + lane * 2];
#pragma unroll
        for (int i = 0; i < 8; ++i) {
            float a = as[(w * 8 + i) * 128 + k];
            acc[i].x = fmaf(a, wv.x, acc[i].x);
            acc[i].y = fmaf(a, wv.y, acc[i].y);
        }
    }

    float2 bb = *(const float2*)&bo[lane * 2];
    float2 gg = *(const float2*)&gamma[lane * 2];
    float2 be = *(const float2*)&beta[lane * 2];

#pragma unroll
    for (int i = 0; i < 8; ++i) {
        int node = base + w * 8 + i;
        if (node >= N) continue;   // wave-uniform branch (node doesn't depend on lane)
        float2 xx = *(const float2*)&x[(size_t)node * 128 + lane * 2];
        float y0 = acc[i].x + bb.x + xx.x;
        float y1 = acc[i].y + bb.y + xx.y;

        float ps = y0 + y1;
#pragma unroll
        for (int m = 1; m < 64; m <<= 1) ps += __shfl_xor(ps, m);
        float mu = ps * (1.0f / 128.0f);

        float d0 = y0 - mu, d1 = y1 - mu;
        float pv = d0 * d0 + d1 * d1;
#pragma unroll
        for (int m = 1; m < 64; m <<= 1) pv += __shfl_xor(pv, m);
        float rstd = rsqrtf(pv * (1.0f / 128.0f) + LN_EPS);

        float o0 = d0 * rstd * gg.x + be.x;
        float o1 = d1 * rstd * gg.y + be.y;
        *(float2*)&out[(size_t)node * 128 + lane * 2] = make_float2(o0, o1);
    }
}

// ---------------------------------------------------------------------------
extern "C" void kernel_launch(void* const* d_in, const int* in_sizes, int n_in,
                              void* d_out, int out_size, void* d_ws, size_t ws_size,
                              hipStream_t stream)
{
    const float* x     = (const float*)d_in[0];
    const int*   ei    = (const int*)d_in[1];
    const float* Wq    = (const float*)d_in[2];
    const float* bq    = (const float*)d_in[3];
    const float* Wk    = (const float*)d_in[4];
    const float* bk    = (const float*)d_in[5];
    const float* Wv    = (const float*)d_in[6];
    const float* bv    = (const float*)d_in[7];
    const float* Wo    = (const float*)d_in[8];
    const float* bo    = (const float*)d_in[9];
    const float* gamma = (const float*)d_in[10];
    const float* beta  = (const float*)d_in[11];
    float* out = (float*)d_out;

    const int N = in_sizes[0] / 128;
    const int E = in_sizes[1] / 2;

    // workspace layout (floats)
    float* Q   = (float*)d_ws;                 // N*128
    float* K   = Q + (size_t)N * 128;          // N*128
    float* V   = K + (size_t)N * 128;          // N*128
    float* agg = V + (size_t)N * 128;          // N*128
    float* S   = agg + (size_t)N * 128;        // E*4
    unsigned* maxbits = (unsigned*)(S + (size_t)E * 4);  // 4
    float* sums = (float*)(maxbits + 4);                 // 4

    hipMemsetAsync(agg, 0, (size_t)N * 128 * sizeof(float), stream);
    hipMemsetAsync(maxbits, 0, 4 * sizeof(unsigned) + 4 * sizeof(float), stream);

    const int nb = (N + 31) / 32;
    qkv_kernel<<<nb, 256, 0, stream>>>(x, Wq, bq, Wk, bk, Wv, bv, Q, K, V, N);
    score_kernel<<<2048, 256, 0, stream>>>(Q, K, ei, E, S, maxbits);
    scatter_kernel<<<2048, 256, 0, stream>>>(V, ei, E, S, maxbits, agg, sums);
    out_kernel<<<nb, 256, 0, stream>>>(x, agg, Wo, bo, gamma, beta, sums, out, N);
}

// Round 2
// 589.615 us; speedup vs baseline: 2.8514x; 2.8514x over previous
//
#include <hip/hip_runtime.h>
#include <math.h>

#define LN_EPS 1e-5f

// ---- monotonic float<->uint key for atomicMax on floats (0 == -inf identity) ----
__device__ __forceinline__ unsigned fkey(float f) {
    unsigned u = __float_as_uint(f);
    return (u & 0x80000000u) ? ~u : (u | 0x80000000u);
}
__device__ __forceinline__ float fkey_dec(unsigned k) {
    unsigned u = (k & 0x80000000u) ? (k ^ 0x80000000u) : ~k;
    return __uint_as_float(u);
}

// ---------------------------------------------------------------------------
// Kernel 1: fused Q/K/V GEMM.  out = x @ W + b for W in {Wq,Wk,Wv}.
// ---------------------------------------------------------------------------
__global__ __launch_bounds__(256) void qkv_kernel(
    const float* __restrict__ x,
    const float* __restrict__ Wq, const float* __restrict__ bq,
    const float* __restrict__ Wk, const float* __restrict__ bk,
    const float* __restrict__ Wv, const float* __restrict__ bv,
    float* __restrict__ Q, float* __restrict__ K, float* __restrict__ V,
    int N)
{
    __shared__ float xs[32 * 128];    // 16 KB
    __shared__ float ws[128 * 128];   // 64 KB
    const int tid  = threadIdx.x;
    const int base = blockIdx.x * 32;

    for (int i = tid; i < 1024; i += 256) {
        int node = i >> 5;
        int c4   = i & 31;
        float4 v = (base + node < N)
                 ? ((const float4*)x)[(size_t)(base + node) * 32 + c4]
                 : make_float4(0.f, 0.f, 0.f, 0.f);
        ((float4*)xs)[i] = v;
    }

    const float* Wm[3] = {Wq, Wk, Wv};
    const float* bm[3] = {bq, bk, bv};
    float*       Om[3] = {Q, K, V};

    const int lane = tid & 63;
    const int w    = tid >> 6;

#pragma unroll
    for (int m = 0; m < 3; ++m) {
        __syncthreads();
        for (int i = tid; i < 4096; i += 256)
            ((float4*)ws)[i] = ((const float4*)Wm[m])[i];
        __syncthreads();

        float2 acc[8];
#pragma unroll
        for (int i = 0; i < 8; ++i) acc[i] = make_float2(0.f, 0.f);

#pragma unroll 4
        for (int k = 0; k < 128; ++k) {
            float2 wv = *(const float2*)&ws[k * 128 + lane * 2];
#pragma unroll
            for (int i = 0; i < 8; ++i) {
                float a = xs[(w * 8 + i) * 128 + k];
                acc[i].x = fmaf(a, wv.x, acc[i].x);
                acc[i].y = fmaf(a, wv.y, acc[i].y);
            }
        }

        float2 bb = *(const float2*)&bm[m][lane * 2];
#pragma unroll
        for (int i = 0; i < 8; ++i) {
            int node = base + w * 8 + i;
            if (node < N) {
                float2 o = make_float2(acc[i].x + bb.x, acc[i].y + bb.y);
                *(float2*)&Om[m][(size_t)node * 128 + lane * 2] = o;
            }
        }
    }
}

// ---------------------------------------------------------------------------
// Kernel 2: per-edge scores + per-head global max + dst histogram.
// 16 lanes per edge; lane j loads float4 j and 16+j of Q[src]/K[dst].
// ---------------------------------------------------------------------------
__global__ __launch_bounds__(256) void score_kernel(
    const float* __restrict__ Q, const float* __restrict__ K,
    const int* __restrict__ ei, int E,
    float* __restrict__ S, unsigned* __restrict__ maxbits,
    unsigned* __restrict__ cnt)
{
    const float scale = 0.17677669529663687f;   // 1/sqrt(32)
    const int tid = threadIdx.x;
    const int j   = tid & 15;
    const int h0  = j >> 3;   // head of the first float4 (0 or 1)

    float lm0 = -3.0e38f, lm1 = -3.0e38f;

    const int egrp    = (blockIdx.x * blockDim.x + tid) >> 4;
    const int estride = (gridDim.x * blockDim.x) >> 4;
    const float4* Q4 = (const float4*)Q;
    const float4* K4 = (const float4*)K;

    for (int e = egrp; e < E; e += estride) {
        int s = ei[e];
        int t = ei[E + e];
        float4 q0 = Q4[(size_t)s * 32 + j];
        float4 q1 = Q4[(size_t)s * 32 + 16 + j];
        float4 k0 = K4[(size_t)t * 32 + j];
        float4 k1 = K4[(size_t)t * 32 + 16 + j];
        float p0 = q0.x * k0.x + q0.y * k0.y + q0.z * k0.z + q0.w * k0.w;
        float p1 = q1.x * k1.x + q1.y * k1.y + q1.z * k1.z + q1.w * k1.w;
#pragma unroll
        for (int m = 1; m <= 4; m <<= 1) {
            p0 += __shfl_xor(p0, m);
            p1 += __shfl_xor(p1, m);
        }
        float s0 = p0 * scale; s0 = (s0 >= 0.f) ? s0 : 0.2f * s0;
        float s1 = p1 * scale; s1 = (s1 >= 0.f) ? s1 : 0.2f * s1;
        lm0 = fmaxf(lm0, s0);
        lm1 = fmaxf(lm1, s1);
        if ((j & 7) == 0) {
            S[(size_t)e * 4 + h0]     = s0;
            S[(size_t)e * 4 + 2 + h0] = s1;
        }
        if (j == 0) atomicAdd(&cnt[t], 1u);   // dst histogram
    }

    __shared__ unsigned smax[4];
    if (tid < 4) smax[tid] = 0u;
    __syncthreads();
    atomicMax(&smax[h0],     fkey(lm0));
    atomicMax(&smax[h0 + 2], fkey(lm1));
    __syncthreads();
    if (tid < 4) atomicMax(&maxbits[tid], smax[tid]);
}

// ---------------------------------------------------------------------------
// Kernel 3: single-block exclusive scan of cnt -> off (CSR) and cursor copy.
// ---------------------------------------------------------------------------
__global__ __launch_bounds__(1024) void scan_kernel(
    const unsigned* __restrict__ cnt, unsigned* __restrict__ off,
    unsigned* __restrict__ cursor, int N)
{
    __shared__ unsigned part[1024];
    const int t = threadIdx.x;
    const int chunk = (N + 1023) / 1024;
    const int lo = t * chunk;
    const int hi = min(lo + chunk, N);

    unsigned s = 0;
    for (int i = lo; i < hi; ++i) s += cnt[i];
    part[t] = s;
    __syncthreads();
    for (int d = 1; d < 1024; d <<= 1) {
        unsigned v = (t >= d) ? part[t - d] : 0u;
        __syncthreads();
        part[t] += v;
        __syncthreads();
    }
    unsigned run = (t == 0) ? 0u : part[t - 1];
    for (int i = lo; i < hi; ++i) {
        off[i] = run; cursor[i] = run; run += cnt[i];
    }
    if (t == 1023) off[N] = part[1023];
}

// ---------------------------------------------------------------------------
// Kernel 4: reorder edges into CSR order; store exp(s - max) per head;
// accumulate per-head global exp-sums.
// ---------------------------------------------------------------------------
__global__ __launch_bounds__(256) void reorder_kernel(
    const int* __restrict__ ei, int E,
    const float4* __restrict__ S4, const unsigned* __restrict__ maxbits,
    unsigned* __restrict__ cursor,
    int* __restrict__ rec_src, float4* __restrict__ rec_a,
    float* __restrict__ sums)
{
    const float gm0 = fkey_dec(maxbits[0]);
    const float gm1 = fkey_dec(maxbits[1]);
    const float gm2 = fkey_dec(maxbits[2]);
    const float gm3 = fkey_dec(maxbits[3]);

    float4 ls = make_float4(0.f, 0.f, 0.f, 0.f);

    for (int e = blockIdx.x * blockDim.x + threadIdx.x; e < E;
         e += gridDim.x * blockDim.x) {
        int s = ei[e];
        int t = ei[E + e];
        float4 sv = S4[e];
        float4 a = make_float4(__expf(sv.x - gm0), __expf(sv.y - gm1),
                               __expf(sv.z - gm2), __expf(sv.w - gm3));
        ls.x += a.x; ls.y += a.y; ls.z += a.z; ls.w += a.w;
        unsigned pos = atomicAdd(&cursor[t], 1u);
        rec_src[pos] = s;
        rec_a[pos]   = a;
    }

    // wave reduce then block reduce then one global atomic per head per block
#pragma unroll
    for (int m = 1; m < 64; m <<= 1) {
        ls.x += __shfl_xor(ls.x, m);
        ls.y += __shfl_xor(ls.y, m);
        ls.z += __shfl_xor(ls.z, m);
        ls.w += __shfl_xor(ls.w, m);
    }
    __shared__ float ssum[4];
    if (threadIdx.x < 4) ssum[threadIdx.x] = 0.f;
    __syncthreads();
    if ((threadIdx.x & 63) == 0) {
        atomicAdd(&ssum[0], ls.x);
        atomicAdd(&ssum[1], ls.y);
        atomicAdd(&ssum[2], ls.z);
        atomicAdd(&ssum[3], ls.w);
    }
    __syncthreads();
    if (threadIdx.x < 4) atomicAdd(&sums[threadIdx.x], ssum[threadIdx.x]);
}

// ---------------------------------------------------------------------------
// Kernel 5: gather-reduce aggregation. One wave per dst node; lane owns 2
// of the 128 output floats. Normalization (1/sum per head) applied here.
// ---------------------------------------------------------------------------
__global__ __launch_bounds__(256) void agg_kernel(
    const float* __restrict__ V,
    const int* __restrict__ rec_src, const float4* __restrict__ rec_a,
    const unsigned* __restrict__ off, const float* __restrict__ sums,
    float* __restrict__ agg, int N)
{
    const int gw = (blockIdx.x * 256 + threadIdx.x) >> 6;  // node id
    if (gw >= N) return;
    const int lane = threadIdx.x & 63;
    const int col  = lane * 2;
    const int h    = lane >> 4;   // head of both cols

    const unsigned lo = off[gw], hi = off[gw + 1];
    float2 acc = make_float2(0.f, 0.f);

    for (unsigned i = lo; i < hi; ++i) {
        int s = rec_src[i];                 // broadcast read
        float4 a4 = rec_a[i];               // broadcast read
        float a = (h == 0) ? a4.x : (h == 1) ? a4.y : (h == 2) ? a4.z : a4.w;
        float2 v = *(const float2*)&V[(size_t)s * 128 + col];  // coalesced 512B/wave
        acc.x = fmaf(a, v.x, acc.x);
        acc.y = fmaf(a, v.y, acc.y);
    }

    float inv = 1.0f / sums[h];
    acc.x *= inv; acc.y *= inv;
    *(float2*)&agg[(size_t)gw * 128 + col] = acc;
}

// ---------------------------------------------------------------------------
// Kernel 6: h = agg @ Wo + bo ; y = x + h ; LayerNorm(y).
// ---------------------------------------------------------------------------
__global__ __launch_bounds__(256) void out_kernel(
    const float* __restrict__ x, const float* __restrict__ agg,
    const float* __restrict__ Wo, const float* __restrict__ bo,
    const float* __restrict__ gamma, const float* __restrict__ beta,
    float* __restrict__ out, int N)
{
    __shared__ float as[32 * 128];    // 16 KB
    __shared__ float ws[128 * 128];   // 64 KB
    const int tid  = threadIdx.x;
    const int base = blockIdx.x * 32;

    for (int i = tid; i < 1024; i += 256) {
        int node = i >> 5, c4 = i & 31;
        float4 v = (base + node < N)
                 ? ((const float4*)agg)[(size_t)(base + node) * 32 + c4]
                 : make_float4(0.f, 0.f, 0.f, 0.f);
        ((float4*)as)[i] = v;
    }
    for (int i = tid; i < 4096; i += 256)
        ((float4*)ws)[i] = ((const float4*)Wo)[i];
    __syncthreads();

    const int lane = tid & 63;
    const int w    = tid >> 6;

    float2 acc[8];
#pragma unroll
    for (int i = 0; i < 8; ++i) acc[i] = make_float2(0.f, 0.f);

#pragma unroll 4
    for (int k = 0; k < 128; ++k) {
        float2 wv = *(const float2*)&ws[k * 128 + lane * 2];
#pragma unroll
        for (int i = 0; i < 8; ++i) {
            float a = as[(w * 8 + i) * 128 + k];
            acc[i].x = fmaf(a, wv.x, acc[i].x);
            acc[i].y = fmaf(a, wv.y, acc[i].y);
        }
    }

    float2 bb = *(const float2*)&bo[lane * 2];
    float2 gg = *(const float2*)&gamma[lane * 2];
    float2 be = *(const float2*)&beta[lane * 2];

#pragma unroll
    for (int i = 0; i < 8; ++i) {
        int node = base + w * 8 + i;
        if (node >= N) continue;
        float2 xx = *(const float2*)&x[(size_t)node * 128 + lane * 2];
        float y0 = acc[i].x + bb.x + xx.x;
        float y1 = acc[i].y + bb.y + xx.y;

        float ps = y0 + y1;
#pragma unroll
        for (int m = 1; m < 64; m <<= 1) ps += __shfl_xor(ps, m);
        float mu = ps * (1.0f / 128.0f);

        float d0 = y0 - mu, d1 = y1 - mu;
        float pv = d0 * d0 + d1 * d1;
#pragma unroll
        for (int m = 1; m < 64; m <<= 1) pv += __shfl_xor(pv, m);
        float rstd = rsqrtf(pv * (1.0f / 128.0f) + LN_EPS);

        float o0 = d0 * rstd * gg.x + be.x;
        float o1 = d1 * rstd * gg.y + be.y;
        *(float2*)&out[(size_t)node * 128 + lane * 2] = make_float2(o0, o1);
    }
}

// ---------------------------------------------------------------------------
extern "C" void kernel_launch(void* const* d_in, const int* in_sizes, int n_in,
                              void* d_out, int out_size, void* d_ws, size_t ws_size,
                              hipStream_t stream)
{
    const float* x     = (const float*)d_in[0];
    const int*   ei    = (const int*)d_in[1];
    const float* Wq    = (const float*)d_in[2];
    const float* bq    = (const float*)d_in[3];
    const float* Wk    = (const float*)d_in[4];
    const float* bk    = (const float*)d_in[5];
    const float* Wv    = (const float*)d_in[6];
    const float* bv    = (const float*)d_in[7];
    const float* Wo    = (const float*)d_in[8];
    const float* bo    = (const float*)d_in[9];
    const float* gamma = (const float*)d_in[10];
    const float* beta  = (const float*)d_in[11];
    float* out = (float*)d_out;

    const int N = in_sizes[0] / 128;
    const int E = in_sizes[1] / 2;

    // workspace layout (4-byte units)
    float* Q   = (float*)d_ws;                 // N*128 floats
    float* K   = Q + (size_t)N * 128;
    float* V   = K + (size_t)N * 128;
    float* agg = V + (size_t)N * 128;
    float* S   = agg + (size_t)N * 128;        // E*4 floats
    unsigned* maxbits = (unsigned*)(S + (size_t)E * 4);  // 4
    float*    sums    = (float*)(maxbits + 4);           // 4
    unsigned* cnt     = (unsigned*)(sums + 4);           // N
    unsigned* off     = cnt + N;                         // N+1
    unsigned* cursor  = off + N + 1;                     // N

    // CSR edge records alias the (dead-after-score) Q buffer:
    // rec_a: E float4 (12.8 MB), rec_src: E int (3.2 MB); Q region is 25.6 MB.
    float4* rec_a   = (float4*)Q;
    int*    rec_src = (int*)(Q + (size_t)E * 4);

    // zero maxbits + sums + cnt (contiguous)
    hipMemsetAsync(maxbits, 0, (size_t)(8 + N) * sizeof(unsigned), stream);

    const int nb = (N + 31) / 32;
    qkv_kernel<<<nb, 256, 0, stream>>>(x, Wq, bq, Wk, bk, Wv, bv, Q, K, V, N);
    score_kernel<<<2048, 256, 0, stream>>>(Q, K, ei, E, S, maxbits, cnt);
    scan_kernel<<<1, 1024, 0, stream>>>(cnt, off, cursor, N);
    reorder_kernel<<<1024, 256, 0, stream>>>(ei, E, (const float4*)S, maxbits,
                                             cursor, rec_src, rec_a, sums);
    agg_kernel<<<(N * 64 + 255) / 256, 256, 0, stream>>>(V, rec_src, rec_a, off,
                                                         sums, agg, N);
    out_kernel<<<nb, 256, 0, stream>>>(x, agg, Wo, bo, gamma, beta, out, N);
}

// Round 3
// 396.858 us; speedup vs baseline: 4.2364x; 1.4857x over previous
//
#include <hip/hip_runtime.h>
#include <math.h>

#define LN_EPS 1e-5f

typedef short short8 __attribute__((ext_vector_type(8)));
typedef float f32x4  __attribute__((ext_vector_type(4)));

// ---- bf16 helpers (bit-level; bf16 = truncated f32, RNE on encode) ----
__device__ __forceinline__ unsigned short f2bf(float f) {
    unsigned u = __float_as_uint(f);
    u += 0x7FFFu + ((u >> 16) & 1u);
    return (unsigned short)(u >> 16);
}
__device__ __forceinline__ unsigned packbf2(float lo, float hi) {
    return (unsigned)f2bf(lo) | ((unsigned)f2bf(hi) << 16);
}
__device__ __forceinline__ float bflo(unsigned u) { return __uint_as_float(u << 16); }
__device__ __forceinline__ float bfhi(unsigned u) { return __uint_as_float(u & 0xFFFF0000u); }

// dot of 2 bf16 pairs packed in uints, accumulated into p
__device__ __forceinline__ float prod2(unsigned qu, unsigned ku, float p) {
    p = fmaf(bflo(qu), bflo(ku), p);
    p = fmaf(bfhi(qu), bfhi(ku), p);
    return p;
}

// ---------------------------------------------------------------------------
// Kernel 0: transpose weights to bf16 W^T  (WT[n][k] = W[k][n]).
// One block per matrix.
// ---------------------------------------------------------------------------
__global__ __launch_bounds__(256) void prep_kernel(
    const float* __restrict__ W0, const float* __restrict__ W1,
    const float* __restrict__ W2, const float* __restrict__ W3,
    unsigned short* __restrict__ T0, unsigned short* __restrict__ T1,
    unsigned short* __restrict__ T2, unsigned short* __restrict__ T3)
{
    const float* W = (blockIdx.x == 0) ? W0 : (blockIdx.x == 1) ? W1
                   : (blockIdx.x == 2) ? W2 : W3;
    unsigned short* T = (blockIdx.x == 0) ? T0 : (blockIdx.x == 1) ? T1
                      : (blockIdx.x == 2) ? T2 : T3;
    const int t = threadIdx.x;
    const int n = (t & 31) * 4;
    for (int k = t >> 5; k < 128; k += 8) {
        float4 w = ((const float4*)W)[k * 32 + (t & 31)];
        T[(n + 0) * 128 + k] = f2bf(w.x);
        T[(n + 1) * 128 + k] = f2bf(w.y);
        T[(n + 2) * 128 + k] = f2bf(w.z);
        T[(n + 3) * 128 + k] = f2bf(w.w);
    }
}

// ---------------------------------------------------------------------------
// Kernel 1: Q/K/V GEMM via bf16 MFMA.  BM=128 rows/block, 4 waves x 32 rows.
// A (x tile) staged in LDS as bf16 with 16B-chunk XOR swizzle (c ^= row&15).
// B fragments read per-lane from bf16 W^T in global (L2-hot, 128KB total).
// Fragment layout (16x16x32): A row = lane&15, k = ko*32 + (lane>>4)*8 + j
// (8 contiguous k); B col = lane&15, same k; D col = lane&15,
// row = 4*(lane>>4) + reg.
// ---------------------------------------------------------------------------
__global__ __launch_bounds__(256) void qkv_mfma(
    const float* __restrict__ x,
    const unsigned short* __restrict__ WqT, const unsigned short* __restrict__ WkT,
    const unsigned short* __restrict__ WvT,
    const float* __restrict__ bq, const float* __restrict__ bk,
    const float* __restrict__ bv,
    unsigned short* __restrict__ Qb, unsigned short* __restrict__ Kb,
    unsigned short* __restrict__ Vb, int N)
{
    __shared__ unsigned short xs[128 * 128];   // 32 KB, swizzled
    const int tid  = threadIdx.x;
    const int base = blockIdx.x * 128;

    // stage x tile: 2048 chunks of 8 bf16 (16B). chunk g: row=g>>4, c=g&15.
    for (int g = tid; g < 2048; g += 256) {
        int row = g >> 4, c = g & 15;
        int node = base + row;
        float4 a, b;
        if (node < N) {
            a = ((const float4*)x)[(size_t)node * 32 + c * 2];
            b = ((const float4*)x)[(size_t)node * 32 + c * 2 + 1];
        } else {
            a = make_float4(0.f, 0.f, 0.f, 0.f);
            b = a;
        }
        uint4 pk;
        pk.x = packbf2(a.x, a.y);
        pk.y = packbf2(a.z, a.w);
        pk.z = packbf2(b.x, b.y);
        pk.w = packbf2(b.z, b.w);
        int sc = c ^ (row & 15);
        *(uint4*)&xs[row * 128 + sc * 8] = pk;
    }
    __syncthreads();

    const int lane = tid & 63;
    const int w    = tid >> 6;      // wave -> rows [w*32, w*32+32)
    const int lr   = lane & 15;
    const int lg   = lane >> 4;

    // A fragments: 2 m-tiles x 4 k-steps
    short8 afrag[2][4];
#pragma unroll
    for (int mt = 0; mt < 2; ++mt) {
#pragma unroll
        for (int ko = 0; ko < 4; ++ko) {
            int row = w * 32 + mt * 16 + lr;
            int sc  = (ko * 4 + lg) ^ lr;
            afrag[mt][ko] = *(const short8*)&xs[row * 128 + sc * 8];
        }
    }

    const unsigned short* WTm[3] = {WqT, WkT, WvT};
    const float*          bm[3]  = {bq, bk, bv};
    unsigned short*       Om[3]  = {Qb, Kb, Vb};

    for (int m = 0; m < 3; ++m) {
        const unsigned short* WT = WTm[m];
        f32x4 acc[2][8];
#pragma unroll
        for (int mt = 0; mt < 2; ++mt)
#pragma unroll
            for (int nt = 0; nt < 8; ++nt)
                acc[mt][nt] = (f32x4){0.f, 0.f, 0.f, 0.f};

#pragma unroll
        for (int nt = 0; nt < 8; ++nt) {
            short8 bfr[4];
#pragma unroll
            for (int ko = 0; ko < 4; ++ko) {
                int n = nt * 16 + lr;
                int k = ko * 32 + lg * 8;
                bfr[ko] = *(const short8*)&WT[n * 128 + k];
            }
#pragma unroll
            for (int mt = 0; mt < 2; ++mt)
#pragma unroll
                for (int ko = 0; ko < 4; ++ko)
                    acc[mt][nt] = __builtin_amdgcn_mfma_f32_16x16x32_bf16(
                        afrag[mt][ko], bfr[ko], acc[mt][nt], 0, 0, 0);
        }

        float bcol[8];
#pragma unroll
        for (int nt = 0; nt < 8; ++nt) bcol[nt] = bm[m][nt * 16 + lr];

        unsigned short* O = Om[m];
#pragma unroll
        for (int mt = 0; mt < 2; ++mt)
#pragma unroll
            for (int i = 0; i < 4; ++i) {
                int node = base + w * 32 + mt * 16 + 4 * lg + i;
                if (node < N) {
#pragma unroll
                    for (int nt = 0; nt < 8; ++nt)
                        O[(size_t)node * 128 + nt * 16 + lr] =
                            f2bf(acc[mt][nt][i] + bcol[nt]);
                }
            }
    }
}

// ---------------------------------------------------------------------------
// Kernel 2: per-edge scores + dst histogram (bf16 Q/K gathers).
// 16 lanes per edge; lane j reads 16B (8 bf16, k = 8j..8j+7) -> head j>>2.
// ---------------------------------------------------------------------------
__global__ __launch_bounds__(256) void score_kernel(
    const unsigned short* __restrict__ Qb, const unsigned short* __restrict__ Kb,
    const int* __restrict__ ei, int E,
    float* __restrict__ S, unsigned* __restrict__ cnt)
{
    const float scale = 0.17677669529663687f;   // 1/sqrt(32)
    const int tid = threadIdx.x;
    const int j   = tid & 15;

    const int egrp    = (blockIdx.x * blockDim.x + tid) >> 4;
    const int estride = (gridDim.x * blockDim.x) >> 4;

    for (int e = egrp; e < E; e += estride) {
        int s = ei[e];
        int t = ei[E + e];
        uint4 q = *(const uint4*)&Qb[(size_t)s * 128 + j * 8];
        uint4 k = *(const uint4*)&Kb[(size_t)t * 128 + j * 8];
        float p = 0.f;
        p = prod2(q.x, k.x, p);
        p = prod2(q.y, k.y, p);
        p = prod2(q.z, k.z, p);
        p = prod2(q.w, k.w, p);
        p += __shfl_xor(p, 1);
        p += __shfl_xor(p, 2);
        float sc = p * scale;
        sc = (sc >= 0.f) ? sc : 0.2f * sc;            // LeakyReLU(0.2)
        if ((j & 3) == 0) S[(size_t)e * 4 + (j >> 2)] = sc;
        if (j == 0) atomicAdd(&cnt[t], 1u);
    }
}

// ---------------------------------------------------------------------------
// Kernel 3: single-block exclusive scan of cnt -> off (CSR) + cursor copy.
// ---------------------------------------------------------------------------
__global__ __launch_bounds__(1024) void scan_kernel(
    const unsigned* __restrict__ cnt, unsigned* __restrict__ off,
    unsigned* __restrict__ cursor, int N)
{
    __shared__ unsigned part[1024];
    const int t = threadIdx.x;
    const int chunk = (N + 1023) / 1024;
    const int lo = t * chunk;
    const int hi = min(lo + chunk, N);

    unsigned s = 0;
    for (int i = lo; i < hi; ++i) s += cnt[i];
    part[t] = s;
    __syncthreads();
    for (int d = 1; d < 1024; d <<= 1) {
        unsigned v = (t >= d) ? part[t - d] : 0u;
        __syncthreads();
        part[t] += v;
        __syncthreads();
    }
    unsigned run = (t == 0) ? 0u : part[t - 1];
    for (int i = lo; i < hi; ++i) {
        off[i] = run; cursor[i] = run; run += cnt[i];
    }
    if (t == 1023) off[N] = part[1023];
}

// ---------------------------------------------------------------------------
// Kernel 4: reorder edges into CSR order; rec_a = exp(s) per head (no max
// subtraction: global softmax, s bounded); accumulate per-head exp-sums.
// ---------------------------------------------------------------------------
__global__ __launch_bounds__(256) void reorder_kernel(
    const int* __restrict__ ei, int E,
    const float4* __restrict__ S4,
    unsigned* __restrict__ cursor,
    int* __restrict__ rec_src, float4* __restrict__ rec_a,
    float* __restrict__ sums)
{
    float4 ls = make_float4(0.f, 0.f, 0.f, 0.f);

    for (int e = blockIdx.x * blockDim.x + threadIdx.x; e < E;
         e += gridDim.x * blockDim.x) {
        int s = ei[e];
        int t = ei[E + e];
        float4 sv = S4[e];
        float4 a = make_float4(__expf(sv.x), __expf(sv.y),
                               __expf(sv.z), __expf(sv.w));
        ls.x += a.x; ls.y += a.y; ls.z += a.z; ls.w += a.w;
        unsigned pos = atomicAdd(&cursor[t], 1u);
        rec_src[pos] = s;
        rec_a[pos]   = a;
    }

#pragma unroll
    for (int m = 1; m < 64; m <<= 1) {
        ls.x += __shfl_xor(ls.x, m);
        ls.y += __shfl_xor(ls.y, m);
        ls.z += __shfl_xor(ls.z, m);
        ls.w += __shfl_xor(ls.w, m);
    }
    __shared__ float ssum[4];
    if (threadIdx.x < 4) ssum[threadIdx.x] = 0.f;
    __syncthreads();
    if ((threadIdx.x & 63) == 0) {
        atomicAdd(&ssum[0], ls.x);
        atomicAdd(&ssum[1], ls.y);
        atomicAdd(&ssum[2], ls.z);
        atomicAdd(&ssum[3], ls.w);
    }
    __syncthreads();
    if (threadIdx.x < 4) atomicAdd(&sums[threadIdx.x], ssum[threadIdx.x]);
}

// ---------------------------------------------------------------------------
// Kernel 5: gather-reduce aggregation (bf16 V). One wave per dst node;
// lane owns 2 cols. Normalized output written as bf16 (MFMA A operand).
// ---------------------------------------------------------------------------
__global__ __launch_bounds__(256) void agg_kernel(
    const unsigned short* __restrict__ Vb,
    const int* __restrict__ rec_src, const float4* __restrict__ rec_a,
    const unsigned* __restrict__ off, const float* __restrict__ sums,
    unsigned short* __restrict__ aggb, int N)
{
    const int gw = (blockIdx.x * 256 + threadIdx.x) >> 6;
    if (gw >= N) return;
    const int lane = threadIdx.x & 63;
    const int col  = lane * 2;
    const int h    = lane >> 4;

    const unsigned lo = off[gw], hi = off[gw + 1];
    float ax = 0.f, ay = 0.f;

    for (unsigned i = lo; i < hi; ++i) {
        int s = rec_src[i];                         // broadcast
        float4 a4 = rec_a[i];                       // broadcast
        float a = (h == 0) ? a4.x : (h == 1) ? a4.y : (h == 2) ? a4.z : a4.w;
        unsigned v = *(const unsigned*)&Vb[(size_t)s * 128 + col];  // 4B coalesced
        ax = fmaf(a, bflo(v), ax);
        ay = fmaf(a, bfhi(v), ay);
    }

    float inv = 1.0f / sums[h];
    *(unsigned*)&aggb[(size_t)gw * 128 + col] = packbf2(ax * inv, ay * inv);
}

// ---------------------------------------------------------------------------
// Kernel 6: h = aggb @ Wo + bo via MFMA; y = x + h; LayerNorm -> out (f32).
// Row r's 128 cols live in the 16 lanes with matching lane>>4 -> LN reduce
// is 8 local nt-sums + shfl_xor(1,2,4,8).
// ---------------------------------------------------------------------------
__global__ __launch_bounds__(256) void out_mfma(
    const float* __restrict__ x, const unsigned short* __restrict__ aggb,
    const unsigned short* __restrict__ WoT,
    const float* __restrict__ bo, const float* __restrict__ gamma,
    const float* __restrict__ beta, float* __restrict__ out, int N)
{
    __shared__ unsigned short as_[128 * 128];   // 32 KB, swizzled
    const int tid  = threadIdx.x;
    const int base = blockIdx.x * 128;

    for (int g = tid; g < 2048; g += 256) {
        int row = g >> 4, c = g & 15;
        int node = base + row;
        uint4 v = (node < N) ? *(const uint4*)&aggb[(size_t)node * 128 + c * 8]
                             : make_uint4(0u, 0u, 0u, 0u);
        int sc = c ^ (row & 15);
        *(uint4*)&as_[row * 128 + sc * 8] = v;
    }
    __syncthreads();

    const int lane = tid & 63;
    const int w    = tid >> 6;
    const int lr   = lane & 15;
    const int lg   = lane >> 4;

    short8 afrag[2][4];
#pragma unroll
    for (int mt = 0; mt < 2; ++mt)
#pragma unroll
        for (int ko = 0; ko < 4; ++ko) {
            int row = w * 32 + mt * 16 + lr;
            int sc  = (ko * 4 + lg) ^ lr;
            afrag[mt][ko] = *(const short8*)&as_[row * 128 + sc * 8];
        }

    f32x4 acc[2][8];
#pragma unroll
    for (int mt = 0; mt < 2; ++mt)
#pragma unroll
        for (int nt = 0; nt < 8; ++nt)
            acc[mt][nt] = (f32x4){0.f, 0.f, 0.f, 0.f};

#pragma unroll
    for (int nt = 0; nt < 8; ++nt) {
        short8 bfr[4];
#pragma unroll
        for (int ko = 0; ko < 4; ++ko) {
            int n = nt * 16 + lr;
            int k = ko * 32 + lg * 8;
            bfr[ko] = *(const short8*)&WoT[n * 128 + k];
        }
#pragma unroll
        for (int mt = 0; mt < 2; ++mt)
#pragma unroll
            for (int ko = 0; ko < 4; ++ko)
                acc[mt][nt] = __builtin_amdgcn_mfma_f32_16x16x32_bf16(
                    afrag[mt][ko], bfr[ko], acc[mt][nt], 0, 0, 0);
    }

    float bo8[8], gg8[8], bb8[8];
#pragma unroll
    for (int nt = 0; nt < 8; ++nt) {
        bo8[nt] = bo[nt * 16 + lr];
        gg8[nt] = gamma[nt * 16 + lr];
        bb8[nt] = beta[nt * 16 + lr];
    }

#pragma unroll
    for (int mt = 0; mt < 2; ++mt)
#pragma unroll
        for (int i = 0; i < 4; ++i) {
            int node = base + w * 32 + mt * 16 + 4 * lg + i;
            if (node >= N) continue;   // uniform within each 16-lane group
            float y8[8];
            float ps = 0.f;
#pragma unroll
            for (int nt = 0; nt < 8; ++nt) {
                float y = acc[mt][nt][i] + bo8[nt]
                        + x[(size_t)node * 128 + nt * 16 + lr];
                y8[nt] = y;
                ps += y;
            }
#pragma unroll
            for (int m = 1; m < 16; m <<= 1) ps += __shfl_xor(ps, m);
            float mu = ps * (1.0f / 128.0f);

            float pv = 0.f;
#pragma unroll
            for (int nt = 0; nt < 8; ++nt) {
                float d = y8[nt] - mu;
                pv = fmaf(d, d, pv);
            }
#pragma unroll
            for (int m = 1; m < 16; m <<= 1) pv += __shfl_xor(pv, m);
            float rstd = rsqrtf(pv * (1.0f / 128.0f) + LN_EPS);

#pragma unroll
            for (int nt = 0; nt < 8; ++nt)
                out[(size_t)node * 128 + nt * 16 + lr] =
                    (y8[nt] - mu) * rstd * gg8[nt] + bb8[nt];
        }
}

// ---------------------------------------------------------------------------
extern "C" void kernel_launch(void* const* d_in, const int* in_sizes, int n_in,
                              void* d_out, int out_size, void* d_ws, size_t ws_size,
                              hipStream_t stream)
{
    const float* x     = (const float*)d_in[0];
    const int*   ei    = (const int*)d_in[1];
    const float* Wq    = (const float*)d_in[2];
    const float* bq    = (const float*)d_in[3];
    const float* Wk    = (const float*)d_in[4];
    const float* bk    = (const float*)d_in[5];
    const float* Wv    = (const float*)d_in[6];
    const float* bv    = (const float*)d_in[7];
    const float* Wo    = (const float*)d_in[8];
    const float* bo    = (const float*)d_in[9];
    const float* gamma = (const float*)d_in[10];
    const float* beta  = (const float*)d_in[11];
    float* out = (float*)d_out;

    const int N = in_sizes[0] / 128;
    const int E = in_sizes[1] / 2;

    // workspace layout
    char* p = (char*)d_ws;
    unsigned short* Qb   = (unsigned short*)p; p += (size_t)N * 128 * 2;
    unsigned short* Kb   = (unsigned short*)p; p += (size_t)N * 128 * 2;
    unsigned short* Vb   = (unsigned short*)p; p += (size_t)N * 128 * 2;
    unsigned short* aggb = (unsigned short*)p; p += (size_t)N * 128 * 2;
    float*  S       = (float*)p;  p += (size_t)E * 4 * 4;
    float4* rec_a   = (float4*)p; p += (size_t)E * 16;
    int*    rec_src = (int*)p;    p += (size_t)E * 4;
    unsigned short* WqT = (unsigned short*)p; p += 16384 * 2;
    unsigned short* WkT = (unsigned short*)p; p += 16384 * 2;
    unsigned short* WvT = (unsigned short*)p; p += 16384 * 2;
    unsigned short* WoT = (unsigned short*)p; p += 16384 * 2;
    float*    sums   = (float*)p;    p += 4 * 4;
    unsigned* cnt    = (unsigned*)p; p += (size_t)N * 4;
    unsigned* off    = (unsigned*)p; p += (size_t)(N + 1) * 4;
    unsigned* cursor = (unsigned*)p;

    // zero sums + cnt (contiguous)
    hipMemsetAsync(sums, 0, (size_t)(4 + N) * sizeof(unsigned), stream);

    const int nb = (N + 127) / 128;
    prep_kernel<<<4, 256, 0, stream>>>(Wq, Wk, Wv, Wo, WqT, WkT, WvT, WoT);
    qkv_mfma<<<nb, 256, 0, stream>>>(x, WqT, WkT, WvT, bq, bk, bv, Qb, Kb, Vb, N);
    score_kernel<<<2048, 256, 0, stream>>>(Qb, Kb, ei, E, S, cnt);
    scan_kernel<<<1, 1024, 0, stream>>>(cnt, off, cursor, N);
    reorder_kernel<<<1024, 256, 0, stream>>>(ei, E, (const float4*)S, cursor,
                                             rec_src, rec_a, sums);
    agg_kernel<<<(N * 64 + 255) / 256, 256, 0, stream>>>(Vb, rec_src, rec_a, off,
                                                         sums, aggb, N);
    out_mfma<<<nb, 256, 0, stream>>>(x, aggb, WoT, bo, gamma, beta, out, N);
}

// Round 4
// 348.736 us; speedup vs baseline: 4.8210x; 1.1380x over previous
//
#include <hip/hip_runtime.h>
#include <math.h>

#define LN_EPS 1e-5f

typedef short short8 __attribute__((ext_vector_type(8)));
typedef float f32x4  __attribute__((ext_vector_type(4)));

// ---- bf16 helpers (bit-level; RNE on encode) ----
__device__ __forceinline__ unsigned short f2bf(float f) {
    unsigned u = __float_as_uint(f);
    u += 0x7FFFu + ((u >> 16) & 1u);
    return (unsigned short)(u >> 16);
}
__device__ __forceinline__ unsigned packbf2(float lo, float hi) {
    return (unsigned)f2bf(lo) | ((unsigned)f2bf(hi) << 16);
}
__device__ __forceinline__ float bflo(unsigned u) { return __uint_as_float(u << 16); }
__device__ __forceinline__ float bfhi(unsigned u) { return __uint_as_float(u & 0xFFFF0000u); }

__device__ __forceinline__ float prod2(unsigned qu, unsigned ku, float p) {
    p = fmaf(bflo(qu), bflo(ku), p);
    p = fmaf(bfhi(qu), bfhi(ku), p);
    return p;
}

// ---------------------------------------------------------------------------
// Kernel 0: transpose weights to bf16 W^T  (WT[n][k] = W[k][n]).
// ---------------------------------------------------------------------------
__global__ __launch_bounds__(256) void prep_kernel(
    const float* __restrict__ W0, const float* __restrict__ W1,
    const float* __restrict__ W2, const float* __restrict__ W3,
    unsigned short* __restrict__ T0, unsigned short* __restrict__ T1,
    unsigned short* __restrict__ T2, unsigned short* __restrict__ T3)
{
    const float* W = (blockIdx.x == 0) ? W0 : (blockIdx.x == 1) ? W1
                   : (blockIdx.x == 2) ? W2 : W3;
    unsigned short* T = (blockIdx.x == 0) ? T0 : (blockIdx.x == 1) ? T1
                      : (blockIdx.x == 2) ? T2 : T3;
    const int t = threadIdx.x;
    const int n = (t & 31) * 4;
    for (int k = t >> 5; k < 128; k += 8) {
        float4 w = ((const float4*)W)[k * 32 + (t & 31)];
        T[(n + 0) * 128 + k] = f2bf(w.x);
        T[(n + 1) * 128 + k] = f2bf(w.y);
        T[(n + 2) * 128 + k] = f2bf(w.z);
        T[(n + 3) * 128 + k] = f2bf(w.w);
    }
}

// ---------------------------------------------------------------------------
// Kernel 1: Q/K/V GEMM via bf16 MFMA.  BM=128 rows/block, 4 waves x 32 rows.
// ---------------------------------------------------------------------------
__global__ __launch_bounds__(256) void qkv_mfma(
    const float* __restrict__ x,
    const unsigned short* __restrict__ WqT, const unsigned short* __restrict__ WkT,
    const unsigned short* __restrict__ WvT,
    const float* __restrict__ bq, const float* __restrict__ bk,
    const float* __restrict__ bv,
    unsigned short* __restrict__ Qb, unsigned short* __restrict__ Kb,
    unsigned short* __restrict__ Vb, int N)
{
    __shared__ unsigned short xs[128 * 128];   // 32 KB, swizzled
    const int tid  = threadIdx.x;
    const int base = blockIdx.x * 128;

    for (int g = tid; g < 2048; g += 256) {
        int row = g >> 4, c = g & 15;
        int node = base + row;
        float4 a, b;
        if (node < N) {
            a = ((const float4*)x)[(size_t)node * 32 + c * 2];
            b = ((const float4*)x)[(size_t)node * 32 + c * 2 + 1];
        } else {
            a = make_float4(0.f, 0.f, 0.f, 0.f);
            b = a;
        }
        uint4 pk;
        pk.x = packbf2(a.x, a.y);
        pk.y = packbf2(a.z, a.w);
        pk.z = packbf2(b.x, b.y);
        pk.w = packbf2(b.z, b.w);
        int sc = c ^ (row & 15);
        *(uint4*)&xs[row * 128 + sc * 8] = pk;
    }
    __syncthreads();

    const int lane = tid & 63;
    const int w    = tid >> 6;
    const int lr   = lane & 15;
    const int lg   = lane >> 4;

    short8 afrag[2][4];
#pragma unroll
    for (int mt = 0; mt < 2; ++mt)
#pragma unroll
        for (int ko = 0; ko < 4; ++ko) {
            int row = w * 32 + mt * 16 + lr;
            int sc  = (ko * 4 + lg) ^ lr;
            afrag[mt][ko] = *(const short8*)&xs[row * 128 + sc * 8];
        }

    const unsigned short* WTm[3] = {WqT, WkT, WvT};
    const float*          bm[3]  = {bq, bk, bv};
    unsigned short*       Om[3]  = {Qb, Kb, Vb};

    for (int m = 0; m < 3; ++m) {
        const unsigned short* WT = WTm[m];
        f32x4 acc[2][8];
#pragma unroll
        for (int mt = 0; mt < 2; ++mt)
#pragma unroll
            for (int nt = 0; nt < 8; ++nt)
                acc[mt][nt] = (f32x4){0.f, 0.f, 0.f, 0.f};

#pragma unroll
        for (int nt = 0; nt < 8; ++nt) {
            short8 bfr[4];
#pragma unroll
            for (int ko = 0; ko < 4; ++ko) {
                int n = nt * 16 + lr;
                int k = ko * 32 + lg * 8;
                bfr[ko] = *(const short8*)&WT[n * 128 + k];
            }
#pragma unroll
            for (int mt = 0; mt < 2; ++mt)
#pragma unroll
                for (int ko = 0; ko < 4; ++ko)
                    acc[mt][nt] = __builtin_amdgcn_mfma_f32_16x16x32_bf16(
                        afrag[mt][ko], bfr[ko], acc[mt][nt], 0, 0, 0);
        }

        float bcol[8];
#pragma unroll
        for (int nt = 0; nt < 8; ++nt) bcol[nt] = bm[m][nt * 16 + lr];

        unsigned short* O = Om[m];
#pragma unroll
        for (int mt = 0; mt < 2; ++mt)
#pragma unroll
            for (int i = 0; i < 4; ++i) {
                int node = base + w * 32 + mt * 16 + 4 * lg + i;
                if (node < N) {
#pragma unroll
                    for (int nt = 0; nt < 8; ++nt)
                        O[(size_t)node * 128 + nt * 16 + lr] =
                            f2bf(acc[mt][nt][i] + bcol[nt]);
                }
            }
    }
}

// ---------------------------------------------------------------------------
// Kernel 2: dst histogram.
// ---------------------------------------------------------------------------
__global__ __launch_bounds__(256) void hist_kernel(
    const int* __restrict__ dst, int E, unsigned* __restrict__ cnt)
{
    for (int e = blockIdx.x * blockDim.x + threadIdx.x; e < E;
         e += gridDim.x * blockDim.x)
        atomicAdd(&cnt[dst[e]], 1u);
}

// ---------------------------------------------------------------------------
// Kernel 3: single-block exclusive scan of cnt -> off (CSR) + cursor copy.
// ---------------------------------------------------------------------------
__global__ __launch_bounds__(1024) void scan_kernel(
    const unsigned* __restrict__ cnt, unsigned* __restrict__ off,
    unsigned* __restrict__ cursor, int N)
{
    __shared__ unsigned part[1024];
    const int t = threadIdx.x;
    const int chunk = (N + 1023) / 1024;
    const int lo = t * chunk;
    const int hi = min(lo + chunk, N);

    unsigned s = 0;
    for (int i = lo; i < hi; ++i) s += cnt[i];
    part[t] = s;
    __syncthreads();
    for (int d = 1; d < 1024; d <<= 1) {
        unsigned v = (t >= d) ? part[t - d] : 0u;
        __syncthreads();
        part[t] += v;
        __syncthreads();
    }
    unsigned run = (t == 0) ? 0u : part[t - 1];
    for (int i = lo; i < hi; ++i) {
        off[i] = run; cursor[i] = run; run += cnt[i];
    }
    if (t == 1023) off[N] = part[1023];
}

// ---------------------------------------------------------------------------
// Kernel 4: reorder edge sources into CSR order (4B records).
// ---------------------------------------------------------------------------
__global__ __launch_bounds__(256) void reorder_kernel(
    const int* __restrict__ ei, int E,
    unsigned* __restrict__ cursor, int* __restrict__ rec_src)
{
    for (int e = blockIdx.x * blockDim.x + threadIdx.x; e < E;
         e += gridDim.x * blockDim.x) {
        int s = ei[e];
        int t = ei[E + e];
        unsigned pos = atomicAdd(&cursor[t], 1u);
        rec_src[pos] = s;
    }
}

// ---------------------------------------------------------------------------
// Kernel 5: fused per-node attention: scores + exp + weighted V aggregation.
// One wave per dst node; 4 edges in flight (groups of 16 lanes); lane j of a
// group owns col chunk [8j, 8j+8) (head j>>2). aggb written UNNORMALIZED;
// per-head exp-sums land in 64 partial buckets (reduced in out_mfma).
// ---------------------------------------------------------------------------
__global__ __launch_bounds__(256) void node_attn_kernel(
    const unsigned short* __restrict__ Qb, const unsigned short* __restrict__ Kb,
    const unsigned short* __restrict__ Vb,
    const int* __restrict__ rec_src, const unsigned* __restrict__ off,
    unsigned short* __restrict__ aggb, float* __restrict__ partials, int N)
{
    const int node = blockIdx.x * 4 + (threadIdx.x >> 6);
    if (node >= N) return;
    const int lane = threadIdx.x & 63;
    const int g = lane >> 4;
    const int j = lane & 15;
    const float scale = 0.17677669529663687f;   // 1/sqrt(32)

    const unsigned lo = off[node], hi = off[node + 1];

    const uint4 kreg = *(const uint4*)&Kb[(size_t)node * 128 + j * 8];

    float acc[8] = {0.f, 0.f, 0.f, 0.f, 0.f, 0.f, 0.f, 0.f};
    float ls = 0.f;

    for (unsigned i = lo; i < hi; i += 4) {
        unsigned e = i + g;
        bool valid = e < hi;
        int s = rec_src[valid ? e : lo];
        uint4 q = *(const uint4*)&Qb[(size_t)s * 128 + j * 8];
        uint4 v = *(const uint4*)&Vb[(size_t)s * 128 + j * 8];
        float p = 0.f;
        p = prod2(q.x, kreg.x, p);
        p = prod2(q.y, kreg.y, p);
        p = prod2(q.z, kreg.z, p);
        p = prod2(q.w, kreg.w, p);
        p += __shfl_xor(p, 1);
        p += __shfl_xor(p, 2);     // head-dot in each 4-lane subgroup
        float sv = p * scale;
        sv = (sv >= 0.f) ? sv : 0.2f * sv;        // LeakyReLU(0.2)
        float a = valid ? __expf(sv) : 0.f;       // global softmax: no max shift
        if ((j & 3) == 0) ls += a;
        acc[0] = fmaf(a, bflo(v.x), acc[0]);
        acc[1] = fmaf(a, bfhi(v.x), acc[1]);
        acc[2] = fmaf(a, bflo(v.y), acc[2]);
        acc[3] = fmaf(a, bfhi(v.y), acc[3]);
        acc[4] = fmaf(a, bflo(v.z), acc[4]);
        acc[5] = fmaf(a, bfhi(v.z), acc[5]);
        acc[6] = fmaf(a, bflo(v.w), acc[6]);
        acc[7] = fmaf(a, bfhi(v.w), acc[7]);
    }

#pragma unroll
    for (int k = 0; k < 8; ++k) {
        acc[k] += __shfl_xor(acc[k], 16);
        acc[k] += __shfl_xor(acc[k], 32);
    }
    ls += __shfl_xor(ls, 16);
    ls += __shfl_xor(ls, 32);

    if (lane < 16) {
        uint4 o;
        o.x = packbf2(acc[0], acc[1]);
        o.y = packbf2(acc[2], acc[3]);
        o.z = packbf2(acc[4], acc[5]);
        o.w = packbf2(acc[6], acc[7]);
        *(uint4*)&aggb[(size_t)node * 128 + j * 8] = o;
        if ((j & 3) == 0)
            atomicAdd(&partials[(blockIdx.x & 63) * 4 + (j >> 2)], ls);
    }
}

// ---------------------------------------------------------------------------
// Kernel 6: h = (aggb * inv_sum) @ Wo + bo via MFMA; y = x + h; LayerNorm.
// inv_sum reduced from the 64x4 partial buckets by wave 0.
// ---------------------------------------------------------------------------
__global__ __launch_bounds__(256) void out_mfma(
    const float* __restrict__ x, const unsigned short* __restrict__ aggb,
    const unsigned short* __restrict__ WoT,
    const float* __restrict__ bo, const float* __restrict__ gamma,
    const float* __restrict__ beta, const float* __restrict__ partials,
    float* __restrict__ out, int N)
{
    __shared__ unsigned short as_[128 * 128];   // 32 KB, swizzled
    __shared__ float invs[4];
    const int tid  = threadIdx.x;
    const int base = blockIdx.x * 128;

    if (tid < 64) {
        float4 ps = ((const float4*)partials)[tid];
#pragma unroll
        for (int m = 1; m < 64; m <<= 1) {
            ps.x += __shfl_xor(ps.x, m);
            ps.y += __shfl_xor(ps.y, m);
            ps.z += __shfl_xor(ps.z, m);
            ps.w += __shfl_xor(ps.w, m);
        }
        if (tid == 0) {
            invs[0] = 1.f / ps.x; invs[1] = 1.f / ps.y;
            invs[2] = 1.f / ps.z; invs[3] = 1.f / ps.w;
        }
    }
    __syncthreads();

    for (int g = tid; g < 2048; g += 256) {
        int row = g >> 4, c = g & 15;
        int node = base + row;
        uint4 v = (node < N) ? *(const uint4*)&aggb[(size_t)node * 128 + c * 8]
                             : make_uint4(0u, 0u, 0u, 0u);
        float iv = invs[c >> 2];   // chunk c covers dims [8c,8c+8) -> head c>>2
        uint4 pk;
        pk.x = packbf2(bflo(v.x) * iv, bfhi(v.x) * iv);
        pk.y = packbf2(bflo(v.y) * iv, bfhi(v.y) * iv);
        pk.z = packbf2(bflo(v.z) * iv, bfhi(v.z) * iv);
        pk.w = packbf2(bflo(v.w) * iv, bfhi(v.w) * iv);
        int sc = c ^ (row & 15);
        *(uint4*)&as_[row * 128 + sc * 8] = pk;
    }
    __syncthreads();

    const int lane = tid & 63;
    const int w    = tid >> 6;
    const int lr   = lane & 15;
    const int lg   = lane >> 4;

    short8 afrag[2][4];
#pragma unroll
    for (int mt = 0; mt < 2; ++mt)
#pragma unroll
        for (int ko = 0; ko < 4; ++ko) {
            int row = w * 32 + mt * 16 + lr;
            int sc  = (ko * 4 + lg) ^ lr;
            afrag[mt][ko] = *(const short8*)&as_[row * 128 + sc * 8];
        }

    f32x4 acc[2][8];
#pragma unroll
    for (int mt = 0; mt < 2; ++mt)
#pragma unroll
        for (int nt = 0; nt < 8; ++nt)
            acc[mt][nt] = (f32x4){0.f, 0.f, 0.f, 0.f};

#pragma unroll
    for (int nt = 0; nt < 8; ++nt) {
        short8 bfr[4];
#pragma unroll
        for (int ko = 0; ko < 4; ++ko) {
            int n = nt * 16 + lr;
            int k = ko * 32 + lg * 8;
            bfr[ko] = *(const short8*)&WoT[n * 128 + k];
        }
#pragma unroll
        for (int mt = 0; mt < 2; ++mt)
#pragma unroll
            for (int ko = 0; ko < 4; ++ko)
                acc[mt][nt] = __builtin_amdgcn_mfma_f32_16x16x32_bf16(
                    afrag[mt][ko], bfr[ko], acc[mt][nt], 0, 0, 0);
    }

    float bo8[8], gg8[8], bb8[8];
#pragma unroll
    for (int nt = 0; nt < 8; ++nt) {
        bo8[nt] = bo[nt * 16 + lr];
        gg8[nt] = gamma[nt * 16 + lr];
        bb8[nt] = beta[nt * 16 + lr];
    }

#pragma unroll
    for (int mt = 0; mt < 2; ++mt)
#pragma unroll
        for (int i = 0; i < 4; ++i) {
            int node = base + w * 32 + mt * 16 + 4 * lg + i;
            if (node >= N) continue;
            float y8[8];
            float ps = 0.f;
#pragma unroll
            for (int nt = 0; nt < 8; ++nt) {
                float y = acc[mt][nt][i] + bo8[nt]
                        + x[(size_t)node * 128 + nt * 16 + lr];
                y8[nt] = y;
                ps += y;
            }
#pragma unroll
            for (int m = 1; m < 16; m <<= 1) ps += __shfl_xor(ps, m);
            float mu = ps * (1.0f / 128.0f);

            float pv = 0.f;
#pragma unroll
            for (int nt = 0; nt < 8; ++nt) {
                float d = y8[nt] - mu;
                pv = fmaf(d, d, pv);
            }
#pragma unroll
            for (int m = 1; m < 16; m <<= 1) pv += __shfl_xor(pv, m);
            float rstd = rsqrtf(pv * (1.0f / 128.0f) + LN_EPS);

#pragma unroll
            for (int nt = 0; nt < 8; ++nt)
                out[(size_t)node * 128 + nt * 16 + lr] =
                    (y8[nt] - mu) * rstd * gg8[nt] + bb8[nt];
        }
}

// ---------------------------------------------------------------------------
extern "C" void kernel_launch(void* const* d_in, const int* in_sizes, int n_in,
                              void* d_out, int out_size, void* d_ws, size_t ws_size,
                              hipStream_t stream)
{
    const float* x     = (const float*)d_in[0];
    const int*   ei    = (const int*)d_in[1];
    const float* Wq    = (const float*)d_in[2];
    const float* bq    = (const float*)d_in[3];
    const float* Wk    = (const float*)d_in[4];
    const float* bk    = (const float*)d_in[5];
    const float* Wv    = (const float*)d_in[6];
    const float* bv    = (const float*)d_in[7];
    const float* Wo    = (const float*)d_in[8];
    const float* bo    = (const float*)d_in[9];
    const float* gamma = (const float*)d_in[10];
    const float* beta  = (const float*)d_in[11];
    float* out = (float*)d_out;

    const int N = in_sizes[0] / 128;
    const int E = in_sizes[1] / 2;

    // workspace layout
    char* p = (char*)d_ws;
    unsigned short* Qb   = (unsigned short*)p; p += (size_t)N * 128 * 2;
    unsigned short* Kb   = (unsigned short*)p; p += (size_t)N * 128 * 2;
    unsigned short* Vb   = (unsigned short*)p; p += (size_t)N * 128 * 2;
    unsigned short* aggb = (unsigned short*)p; p += (size_t)N * 128 * 2;
    int* rec_src = (int*)p; p += (size_t)E * 4;
    unsigned short* WqT = (unsigned short*)p; p += 16384 * 2;
    unsigned short* WkT = (unsigned short*)p; p += 16384 * 2;
    unsigned short* WvT = (unsigned short*)p; p += 16384 * 2;
    unsigned short* WoT = (unsigned short*)p; p += 16384 * 2;
    float*    partials = (float*)p;  p += 256 * 4;          // 64 buckets x 4 heads
    unsigned* cnt      = (unsigned*)p; p += (size_t)N * 4;
    unsigned* off      = (unsigned*)p; p += (size_t)(N + 1) * 4;
    unsigned* cursor   = (unsigned*)p;

    // zero partials + cnt (contiguous)
    hipMemsetAsync(partials, 0, (size_t)(256 + N) * sizeof(unsigned), stream);

    const int nb = (N + 127) / 128;
    prep_kernel<<<4, 256, 0, stream>>>(Wq, Wk, Wv, Wo, WqT, WkT, WvT, WoT);
    qkv_mfma<<<nb, 256, 0, stream>>>(x, WqT, WkT, WvT, bq, bk, bv, Qb, Kb, Vb, N);
    hist_kernel<<<1024, 256, 0, stream>>>(ei + E, E, cnt);
    scan_kernel<<<1, 1024, 0, stream>>>(cnt, off, cursor, N);
    reorder_kernel<<<1024, 256, 0, stream>>>(ei, E, cursor, rec_src);
    node_attn_kernel<<<(N + 3) / 4, 256, 0, stream>>>(Qb, Kb, Vb, rec_src, off,
                                                      aggb, partials, N);
    out_mfma<<<nb, 256, 0, stream>>>(x, aggb, WoT, bo, gamma, beta, partials,
                                     out, N);
}

// Round 5
// 268.746 us; speedup vs baseline: 6.2559x; 1.2976x over previous
//
#include <hip/hip_runtime.h>
#include <math.h>

#define LN_EPS 1e-5f

typedef short short8 __attribute__((ext_vector_type(8)));
typedef float f32x4  __attribute__((ext_vector_type(4)));

// ---- bf16 helpers (bit-level; RNE on encode) ----
__device__ __forceinline__ unsigned short f2bf(float f) {
    unsigned u = __float_as_uint(f);
    u += 0x7FFFu + ((u >> 16) & 1u);
    return (unsigned short)(u >> 16);
}
__device__ __forceinline__ unsigned packbf2(float lo, float hi) {
    return (unsigned)f2bf(lo) | ((unsigned)f2bf(hi) << 16);
}
__device__ __forceinline__ float bflo(unsigned u) { return __uint_as_float(u << 16); }
__device__ __forceinline__ float bfhi(unsigned u) { return __uint_as_float(u & 0xFFFF0000u); }

__device__ __forceinline__ float prod2(unsigned qu, unsigned ku, float p) {
    p = fmaf(bflo(qu), bflo(ku), p);
    p = fmaf(bfhi(qu), bfhi(ku), p);
    return p;
}

// ---------------------------------------------------------------------------
// Kernel 0: transpose weights to bf16 W^T  (WT[n][k] = W[k][n]).
// ---------------------------------------------------------------------------
__global__ __launch_bounds__(256) void prep_kernel(
    const float* __restrict__ W0, const float* __restrict__ W1,
    const float* __restrict__ W2, const float* __restrict__ W3,
    unsigned short* __restrict__ T0, unsigned short* __restrict__ T1,
    unsigned short* __restrict__ T2, unsigned short* __restrict__ T3)
{
    const float* W = (blockIdx.x == 0) ? W0 : (blockIdx.x == 1) ? W1
                   : (blockIdx.x == 2) ? W2 : W3;
    unsigned short* T = (blockIdx.x == 0) ? T0 : (blockIdx.x == 1) ? T1
                      : (blockIdx.x == 2) ? T2 : T3;
    const int t = threadIdx.x;
    const int n = (t & 31) * 4;
    for (int k = t >> 5; k < 128; k += 8) {
        float4 w = ((const float4*)W)[k * 32 + (t & 31)];
        T[(n + 0) * 128 + k] = f2bf(w.x);
        T[(n + 1) * 128 + k] = f2bf(w.y);
        T[(n + 2) * 128 + k] = f2bf(w.z);
        T[(n + 3) * 128 + k] = f2bf(w.w);
    }
}

// ---------------------------------------------------------------------------
// Kernel 1: Q/K/V GEMM via bf16 MFMA.  BM=128 rows/block, 4 waves x 32 rows.
// ---------------------------------------------------------------------------
__global__ __launch_bounds__(256) void qkv_mfma(
    const float* __restrict__ x,
    const unsigned short* __restrict__ WqT, const unsigned short* __restrict__ WkT,
    const unsigned short* __restrict__ WvT,
    const float* __restrict__ bq, const float* __restrict__ bk,
    const float* __restrict__ bv,
    unsigned short* __restrict__ Qb, unsigned short* __restrict__ Kb,
    unsigned short* __restrict__ Vb, int N)
{
    __shared__ unsigned short xs[128 * 128];   // 32 KB, swizzled
    const int tid  = threadIdx.x;
    const int base = blockIdx.x * 128;

    for (int g = tid; g < 2048; g += 256) {
        int row = g >> 4, c = g & 15;
        int node = base + row;
        float4 a, b;
        if (node < N) {
            a = ((const float4*)x)[(size_t)node * 32 + c * 2];
            b = ((const float4*)x)[(size_t)node * 32 + c * 2 + 1];
        } else {
            a = make_float4(0.f, 0.f, 0.f, 0.f);
            b = a;
        }
        uint4 pk;
        pk.x = packbf2(a.x, a.y);
        pk.y = packbf2(a.z, a.w);
        pk.z = packbf2(b.x, b.y);
        pk.w = packbf2(b.z, b.w);
        int sc = c ^ (row & 15);
        *(uint4*)&xs[row * 128 + sc * 8] = pk;
    }
    __syncthreads();

    const int lane = tid & 63;
    const int w    = tid >> 6;
    const int lr   = lane & 15;
    const int lg   = lane >> 4;

    short8 afrag[2][4];
#pragma unroll
    for (int mt = 0; mt < 2; ++mt)
#pragma unroll
        for (int ko = 0; ko < 4; ++ko) {
            int row = w * 32 + mt * 16 + lr;
            int sc  = (ko * 4 + lg) ^ lr;
            afrag[mt][ko] = *(const short8*)&xs[row * 128 + sc * 8];
        }

    const unsigned short* WTm[3] = {WqT, WkT, WvT};
    const float*          bm[3]  = {bq, bk, bv};
    unsigned short*       Om[3]  = {Qb, Kb, Vb};

    for (int m = 0; m < 3; ++m) {
        const unsigned short* WT = WTm[m];
        f32x4 acc[2][8];
#pragma unroll
        for (int mt = 0; mt < 2; ++mt)
#pragma unroll
            for (int nt = 0; nt < 8; ++nt)
                acc[mt][nt] = (f32x4){0.f, 0.f, 0.f, 0.f};

#pragma unroll
        for (int nt = 0; nt < 8; ++nt) {
            short8 bfr[4];
#pragma unroll
            for (int ko = 0; ko < 4; ++ko) {
                int n = nt * 16 + lr;
                int k = ko * 32 + lg * 8;
                bfr[ko] = *(const short8*)&WT[n * 128 + k];
            }
#pragma unroll
            for (int mt = 0; mt < 2; ++mt)
#pragma unroll
                for (int ko = 0; ko < 4; ++ko)
                    acc[mt][nt] = __builtin_amdgcn_mfma_f32_16x16x32_bf16(
                        afrag[mt][ko], bfr[ko], acc[mt][nt], 0, 0, 0);
        }

        float bcol[8];
#pragma unroll
        for (int nt = 0; nt < 8; ++nt) bcol[nt] = bm[m][nt * 16 + lr];

        unsigned short* O = Om[m];
#pragma unroll
        for (int mt = 0; mt < 2; ++mt)
#pragma unroll
            for (int i = 0; i < 4; ++i) {
                int node = base + w * 32 + mt * 16 + 4 * lg + i;
                if (node < N) {
#pragma unroll
                    for (int nt = 0; nt < 8; ++nt)
                        O[(size_t)node * 128 + nt * 16 + lr] =
                            f2bf(acc[mt][nt][i] + bcol[nt]);
                }
            }
    }
}

// ---------------------------------------------------------------------------
// Kernel 2: dst histogram.
// ---------------------------------------------------------------------------
__global__ __launch_bounds__(256) void hist_kernel(
    const int* __restrict__ dst, int E, unsigned* __restrict__ cnt)
{
    for (int e = blockIdx.x * blockDim.x + threadIdx.x; e < E;
         e += gridDim.x * blockDim.x)
        atomicAdd(&cnt[dst[e]], 1u);
}

// ---------------------------------------------------------------------------
// Kernel 3a: per-chunk exclusive scan (1024 elements/block) + block totals.
// ---------------------------------------------------------------------------
__global__ __launch_bounds__(1024) void scan1_kernel(
    const unsigned* __restrict__ cnt, unsigned* __restrict__ off,
    unsigned* __restrict__ bsum, int N)
{
    __shared__ unsigned sh[1024];
    const int t = threadIdx.x;
    const int gid = blockIdx.x * 1024 + t;
    unsigned v = (gid < N) ? cnt[gid] : 0u;
    sh[t] = v;
    __syncthreads();
#pragma unroll
    for (int d = 1; d < 1024; d <<= 1) {
        unsigned u = (t >= d) ? sh[t - d] : 0u;
        __syncthreads();
        sh[t] += u;
        __syncthreads();
    }
    if (gid < N) off[gid] = sh[t] - v;          // exclusive within chunk
    if (t == 1023) bsum[blockIdx.x] = sh[1023]; // chunk total
}

// ---------------------------------------------------------------------------
// Kernel 3b: scan block totals (single small block, nb <= 1024); off[N]=total.
// ---------------------------------------------------------------------------
__global__ __launch_bounds__(1024) void scan2_kernel(
    const unsigned* __restrict__ bsum, unsigned* __restrict__ bbase,
    unsigned* __restrict__ off, int nb, int N)
{
    __shared__ unsigned sh[1024];
    const int t = threadIdx.x;
    unsigned v = (t < nb) ? bsum[t] : 0u;
    sh[t] = v;
    __syncthreads();
#pragma unroll
    for (int d = 1; d < 1024; d <<= 1) {
        unsigned u = (t >= d) ? sh[t - d] : 0u;
        __syncthreads();
        sh[t] += u;
        __syncthreads();
    }
    if (t < nb) bbase[t] = sh[t] - v;
    if (t == 1023) off[N] = sh[1023];
}

// ---------------------------------------------------------------------------
// Kernel 3c: add chunk base; write cursor copy.
// ---------------------------------------------------------------------------
__global__ __launch_bounds__(1024) void scan3_kernel(
    unsigned* __restrict__ off, unsigned* __restrict__ cursor,
    const unsigned* __restrict__ bbase, int N)
{
    const int gid = blockIdx.x * 1024 + threadIdx.x;
    if (gid < N) {
        unsigned o = off[gid] + bbase[blockIdx.x];
        off[gid] = o;
        cursor[gid] = o;
    }
}

// ---------------------------------------------------------------------------
// Kernel 4: reorder edge sources into CSR order (4B records).
// ---------------------------------------------------------------------------
__global__ __launch_bounds__(256) void reorder_kernel(
    const int* __restrict__ ei, int E,
    unsigned* __restrict__ cursor, int* __restrict__ rec_src)
{
    for (int e = blockIdx.x * blockDim.x + threadIdx.x; e < E;
         e += gridDim.x * blockDim.x) {
        int s = ei[e];
        int t = ei[E + e];
        unsigned pos = atomicAdd(&cursor[t], 1u);
        rec_src[pos] = s;
    }
}

// ---------------------------------------------------------------------------
// Kernel 5: fused per-node attention: scores + exp + weighted V aggregation.
// One wave per dst node; 4 edges in flight (groups of 16 lanes); lane j of a
// group owns col chunk [8j, 8j+8) (head j>>2). aggb written UNNORMALIZED;
// per-head exp-sums land in 64 partial buckets (reduced in out_mfma).
// ---------------------------------------------------------------------------
__global__ __launch_bounds__(256) void node_attn_kernel(
    const unsigned short* __restrict__ Qb, const unsigned short* __restrict__ Kb,
    const unsigned short* __restrict__ Vb,
    const int* __restrict__ rec_src, const unsigned* __restrict__ off,
    unsigned short* __restrict__ aggb, float* __restrict__ partials, int N)
{
    const int node = blockIdx.x * 4 + (threadIdx.x >> 6);
    if (node >= N) return;
    const int lane = threadIdx.x & 63;
    const int g = lane >> 4;
    const int j = lane & 15;
    const float scale = 0.17677669529663687f;   // 1/sqrt(32)

    const unsigned lo = off[node], hi = off[node + 1];

    const uint4 kreg = *(const uint4*)&Kb[(size_t)node * 128 + j * 8];

    float acc[8] = {0.f, 0.f, 0.f, 0.f, 0.f, 0.f, 0.f, 0.f};
    float ls = 0.f;

    for (unsigned i = lo; i < hi; i += 4) {
        unsigned e = i + g;
        bool valid = e < hi;
        int s = rec_src[valid ? e : lo];
        uint4 q = *(const uint4*)&Qb[(size_t)s * 128 + j * 8];
        uint4 v = *(const uint4*)&Vb[(size_t)s * 128 + j * 8];
        float p = 0.f;
        p = prod2(q.x, kreg.x, p);
        p = prod2(q.y, kreg.y, p);
        p = prod2(q.z, kreg.z, p);
        p = prod2(q.w, kreg.w, p);
        p += __shfl_xor(p, 1);
        p += __shfl_xor(p, 2);     // head-dot in each 4-lane subgroup
        float sv = p * scale;
        sv = (sv >= 0.f) ? sv : 0.2f * sv;        // LeakyReLU(0.2)
        float a = valid ? __expf(sv) : 0.f;       // global softmax: no max shift
        if ((j & 3) == 0) ls += a;
        acc[0] = fmaf(a, bflo(v.x), acc[0]);
        acc[1] = fmaf(a, bfhi(v.x), acc[1]);
        acc[2] = fmaf(a, bflo(v.y), acc[2]);
        acc[3] = fmaf(a, bfhi(v.y), acc[3]);
        acc[4] = fmaf(a, bflo(v.z), acc[4]);
        acc[5] = fmaf(a, bfhi(v.z), acc[5]);
        acc[6] = fmaf(a, bflo(v.w), acc[6]);
        acc[7] = fmaf(a, bfhi(v.w), acc[7]);
    }

#pragma unroll
    for (int k = 0; k < 8; ++k) {
        acc[k] += __shfl_xor(acc[k], 16);
        acc[k] += __shfl_xor(acc[k], 32);
    }
    ls += __shfl_xor(ls, 16);
    ls += __shfl_xor(ls, 32);

    if (lane < 16) {
        uint4 o;
        o.x = packbf2(acc[0], acc[1]);
        o.y = packbf2(acc[2], acc[3]);
        o.z = packbf2(acc[4], acc[5]);
        o.w = packbf2(acc[6], acc[7]);
        *(uint4*)&aggb[(size_t)node * 128 + j * 8] = o;
        if ((j & 3) == 0)
            atomicAdd(&partials[(blockIdx.x & 63) * 4 + (j >> 2)], ls);
    }
}

// ---------------------------------------------------------------------------
// Kernel 6: h = (aggb * inv_sum) @ Wo + bo via MFMA; y = x + h; LayerNorm.
// ---------------------------------------------------------------------------
__global__ __launch_bounds__(256) void out_mfma(
    const float* __restrict__ x, const unsigned short* __restrict__ aggb,
    const unsigned short* __restrict__ WoT,
    const float* __restrict__ bo, const float* __restrict__ gamma,
    const float* __restrict__ beta, const float* __restrict__ partials,
    float* __restrict__ out, int N)
{
    __shared__ unsigned short as_[128 * 128];   // 32 KB, swizzled
    __shared__ float invs[4];
    const int tid  = threadIdx.x;
    const int base = blockIdx.x * 128;

    if (tid < 64) {
        float4 ps = ((const float4*)partials)[tid];
#pragma unroll
        for (int m = 1; m < 64; m <<= 1) {
            ps.x += __shfl_xor(ps.x, m);
            ps.y += __shfl_xor(ps.y, m);
            ps.z += __shfl_xor(ps.z, m);
            ps.w += __shfl_xor(ps.w, m);
        }
        if (tid == 0) {
            invs[0] = 1.f / ps.x; invs[1] = 1.f / ps.y;
            invs[2] = 1.f / ps.z; invs[3] = 1.f / ps.w;
        }
    }
    __syncthreads();

    for (int g = tid; g < 2048; g += 256) {
        int row = g >> 4, c = g & 15;
        int node = base + row;
        uint4 v = (node < N) ? *(const uint4*)&aggb[(size_t)node * 128 + c * 8]
                             : make_uint4(0u, 0u, 0u, 0u);
        float iv = invs[c >> 2];   // chunk c covers dims [8c,8c+8) -> head c>>2
        uint4 pk;
        pk.x = packbf2(bflo(v.x) * iv, bfhi(v.x) * iv);
        pk.y = packbf2(bflo(v.y) * iv, bfhi(v.y) * iv);
        pk.z = packbf2(bflo(v.z) * iv, bfhi(v.z) * iv);
        pk.w = packbf2(bflo(v.w) * iv, bfhi(v.w) * iv);
        int sc = c ^ (row & 15);
        *(uint4*)&as_[row * 128 + sc * 8] = pk;
    }
    __syncthreads();

    const int lane = tid & 63;
    const int w    = tid >> 6;
    const int lr   = lane & 15;
    const int lg   = lane >> 4;

    short8 afrag[2][4];
#pragma unroll
    for (int mt = 0; mt < 2; ++mt)
#pragma unroll
        for (int ko = 0; ko < 4; ++ko) {
            int row = w * 32 + mt * 16 + lr;
            int sc  = (ko * 4 + lg) ^ lr;
            afrag[mt][ko] = *(const short8*)&as_[row * 128 + sc * 8];
        }

    f32x4 acc[2][8];
#pragma unroll
    for (int mt = 0; mt < 2; ++mt)
#pragma unroll
        for (int nt = 0; nt < 8; ++nt)
            acc[mt][nt] = (f32x4){0.f, 0.f, 0.f, 0.f};

#pragma unroll
    for (int nt = 0; nt < 8; ++nt) {
        short8 bfr[4];
#pragma unroll
        for (int ko = 0; ko < 4; ++ko) {
            int n = nt * 16 + lr;
            int k = ko * 32 + lg * 8;
            bfr[ko] = *(const short8*)&WoT[n * 128 + k];
        }
#pragma unroll
        for (int mt = 0; mt < 2; ++mt)
#pragma unroll
            for (int ko = 0; ko < 4; ++ko)
                acc[mt][nt] = __builtin_amdgcn_mfma_f32_16x16x32_bf16(
                    afrag[mt][ko], bfr[ko], acc[mt][nt], 0, 0, 0);
    }

    float bo8[8], gg8[8], bb8[8];
#pragma unroll
    for (int nt = 0; nt < 8; ++nt) {
        bo8[nt] = bo[nt * 16 + lr];
        gg8[nt] = gamma[nt * 16 + lr];
        bb8[nt] = beta[nt * 16 + lr];
    }

#pragma unroll
    for (int mt = 0; mt < 2; ++mt)
#pragma unroll
        for (int i = 0; i < 4; ++i) {
            int node = base + w * 32 + mt * 16 + 4 * lg + i;
            if (node >= N) continue;
            float y8[8];
            float ps = 0.f;
#pragma unroll
            for (int nt = 0; nt < 8; ++nt) {
                float y = acc[mt][nt][i] + bo8[nt]
                        + x[(size_t)node * 128 + nt * 16 + lr];
                y8[nt] = y;
                ps += y;
            }
#pragma unroll
            for (int m = 1; m < 16; m <<= 1) ps += __shfl_xor(ps, m);
            float mu = ps * (1.0f / 128.0f);

            float pv = 0.f;
#pragma unroll
            for (int nt = 0; nt < 8; ++nt) {
                float d = y8[nt] - mu;
                pv = fmaf(d, d, pv);
            }
#pragma unroll
            for (int m = 1; m < 16; m <<= 1) pv += __shfl_xor(pv, m);
            float rstd = rsqrtf(pv * (1.0f / 128.0f) + LN_EPS);

#pragma unroll
            for (int nt = 0; nt < 8; ++nt)
                out[(size_t)node * 128 + nt * 16 + lr] =
                    (y8[nt] - mu) * rstd * gg8[nt] + bb8[nt];
        }
}

// ---------------------------------------------------------------------------
extern "C" void kernel_launch(void* const* d_in, const int* in_sizes, int n_in,
                              void* d_out, int out_size, void* d_ws, size_t ws_size,
                              hipStream_t stream)
{
    const float* x     = (const float*)d_in[0];
    const int*   ei    = (const int*)d_in[1];
    const float* Wq    = (const float*)d_in[2];
    const float* bq    = (const float*)d_in[3];
    const float* Wk    = (const float*)d_in[4];
    const float* bk    = (const float*)d_in[5];
    const float* Wv    = (const float*)d_in[6];
    const float* bv    = (const float*)d_in[7];
    const float* Wo    = (const float*)d_in[8];
    const float* bo    = (const float*)d_in[9];
    const float* gamma = (const float*)d_in[10];
    const float* beta  = (const float*)d_in[11];
    float* out = (float*)d_out;

    const int N = in_sizes[0] / 128;
    const int E = in_sizes[1] / 2;

    // workspace layout
    char* p = (char*)d_ws;
    unsigned short* Qb   = (unsigned short*)p; p += (size_t)N * 128 * 2;
    unsigned short* Kb   = (unsigned short*)p; p += (size_t)N * 128 * 2;
    unsigned short* Vb   = (unsigned short*)p; p += (size_t)N * 128 * 2;
    unsigned short* aggb = (unsigned short*)p; p += (size_t)N * 128 * 2;
    int* rec_src = (int*)p; p += (size_t)E * 4;
    unsigned short* WqT = (unsigned short*)p; p += 16384 * 2;
    unsigned short* WkT = (unsigned short*)p; p += 16384 * 2;
    unsigned short* WvT = (unsigned short*)p; p += 16384 * 2;
    unsigned short* WoT = (unsigned short*)p; p += 16384 * 2;
    float*    partials = (float*)p;  p += 256 * 4;          // 64 buckets x 4 heads
    unsigned* cnt      = (unsigned*)p; p += (size_t)N * 4;
    unsigned* off      = (unsigned*)p; p += (size_t)(N + 1) * 4;
    unsigned* cursor   = (unsigned*)p; p += (size_t)N * 4;
    unsigned* bsum     = (unsigned*)p; p += 1024 * 4;
    unsigned* bbase    = (unsigned*)p;

    // zero partials + cnt (contiguous)
    hipMemsetAsync(partials, 0, (size_t)(256 + N) * sizeof(unsigned), stream);

    const int nb  = (N + 127) / 128;
    const int nsc = (N + 1023) / 1024;
    prep_kernel<<<4, 256, 0, stream>>>(Wq, Wk, Wv, Wo, WqT, WkT, WvT, WoT);
    qkv_mfma<<<nb, 256, 0, stream>>>(x, WqT, WkT, WvT, bq, bk, bv, Qb, Kb, Vb, N);
    hist_kernel<<<1024, 256, 0, stream>>>(ei + E, E, cnt);
    scan1_kernel<<<nsc, 1024, 0, stream>>>(cnt, off, bsum, N);
    scan2_kernel<<<1, 1024, 0, stream>>>(bsum, bbase, off, nsc, N);
    scan3_kernel<<<nsc, 1024, 0, stream>>>(off, cursor, bbase, N);
    reorder_kernel<<<1024, 256, 0, stream>>>(ei, E, cursor, rec_src);
    node_attn_kernel<<<(N + 3) / 4, 256, 0, stream>>>(Qb, Kb, Vb, rec_src, off,
                                                      aggb, partials, N);
    out_mfma<<<nb, 256, 0, stream>>>(x, aggb, WoT, bo, gamma, beta, partials,
                                     out, N);
}

// Round 6
// 263.836 us; speedup vs baseline: 6.3723x; 1.0186x over previous
//
#include <hip/hip_runtime.h>
#include <math.h>

#define LN_EPS 1e-5f

typedef short short8 __attribute__((ext_vector_type(8)));
typedef float f32x4  __attribute__((ext_vector_type(4)));

// ---- bf16 helpers (bit-level; RNE on encode) ----
__device__ __forceinline__ unsigned short f2bf(float f) {
    unsigned u = __float_as_uint(f);
    u += 0x7FFFu + ((u >> 16) & 1u);
    return (unsigned short)(u >> 16);
}
__device__ __forceinline__ unsigned packbf2(float lo, float hi) {
    return (unsigned)f2bf(lo) | ((unsigned)f2bf(hi) << 16);
}
__device__ __forceinline__ float bflo(unsigned u) { return __uint_as_float(u << 16); }
__device__ __forceinline__ float bfhi(unsigned u) { return __uint_as_float(u & 0xFFFF0000u); }

__device__ __forceinline__ float prod2(unsigned qu, unsigned ku, float p) {
    p = fmaf(bflo(qu), bflo(ku), p);
    p = fmaf(bfhi(qu), bfhi(ku), p);
    return p;
}

// ---------------------------------------------------------------------------
// Kernel 0: transpose weights to bf16 W^T  (WT[n][k] = W[k][n]).
// ---------------------------------------------------------------------------
__global__ __launch_bounds__(256) void prep_kernel(
    const float* __restrict__ W0, const float* __restrict__ W1,
    const float* __restrict__ W2, const float* __restrict__ W3,
    unsigned short* __restrict__ T0, unsigned short* __restrict__ T1,
    unsigned short* __restrict__ T2, unsigned short* __restrict__ T3)
{
    const float* W = (blockIdx.x == 0) ? W0 : (blockIdx.x == 1) ? W1
                   : (blockIdx.x == 2) ? W2 : W3;
    unsigned short* T = (blockIdx.x == 0) ? T0 : (blockIdx.x == 1) ? T1
                      : (blockIdx.x == 2) ? T2 : T3;
    const int t = threadIdx.x;
    const int n = (t & 31) * 4;
    for (int k = t >> 5; k < 128; k += 8) {
        float4 w = ((const float4*)W)[k * 32 + (t & 31)];
        T[(n + 0) * 128 + k] = f2bf(w.x);
        T[(n + 1) * 128 + k] = f2bf(w.y);
        T[(n + 2) * 128 + k] = f2bf(w.z);
        T[(n + 3) * 128 + k] = f2bf(w.w);
    }
}

// ---------------------------------------------------------------------------
// Kernel 1: Q/K/V GEMM via bf16 MFMA.  BM=128 rows/block, 4 waves x 32 rows.
// Q and V are written INTERLEAVED into QVb: node record = 256 bf16
// (Q dims 0..127, V dims 128..255). K goes to its own [node][128] buffer.
// ---------------------------------------------------------------------------
__global__ __launch_bounds__(256) void qkv_mfma(
    const float* __restrict__ x,
    const unsigned short* __restrict__ WqT, const unsigned short* __restrict__ WkT,
    const unsigned short* __restrict__ WvT,
    const float* __restrict__ bq, const float* __restrict__ bk,
    const float* __restrict__ bv,
    unsigned short* __restrict__ QVb, unsigned short* __restrict__ Kb, int N)
{
    __shared__ unsigned short xs[128 * 128];   // 32 KB, swizzled
    const int tid  = threadIdx.x;
    const int base = blockIdx.x * 128;

    for (int g = tid; g < 2048; g += 256) {
        int row = g >> 4, c = g & 15;
        int node = base + row;
        float4 a, b;
        if (node < N) {
            a = ((const float4*)x)[(size_t)node * 32 + c * 2];
            b = ((const float4*)x)[(size_t)node * 32 + c * 2 + 1];
        } else {
            a = make_float4(0.f, 0.f, 0.f, 0.f);
            b = a;
        }
        uint4 pk;
        pk.x = packbf2(a.x, a.y);
        pk.y = packbf2(a.z, a.w);
        pk.z = packbf2(b.x, b.y);
        pk.w = packbf2(b.z, b.w);
        int sc = c ^ (row & 15);
        *(uint4*)&xs[row * 128 + sc * 8] = pk;
    }
    __syncthreads();

    const int lane = tid & 63;
    const int w    = tid >> 6;
    const int lr   = lane & 15;
    const int lg   = lane >> 4;

    short8 afrag[2][4];
#pragma unroll
    for (int mt = 0; mt < 2; ++mt)
#pragma unroll
        for (int ko = 0; ko < 4; ++ko) {
            int row = w * 32 + mt * 16 + lr;
            int sc  = (ko * 4 + lg) ^ lr;
            afrag[mt][ko] = *(const short8*)&xs[row * 128 + sc * 8];
        }

    const unsigned short* WTm[3] = {WqT, WkT, WvT};
    const float*          bm[3]  = {bq, bk, bv};

    for (int m = 0; m < 3; ++m) {
        const unsigned short* WT = WTm[m];
        f32x4 acc[2][8];
#pragma unroll
        for (int mt = 0; mt < 2; ++mt)
#pragma unroll
            for (int nt = 0; nt < 8; ++nt)
                acc[mt][nt] = (f32x4){0.f, 0.f, 0.f, 0.f};

#pragma unroll
        for (int nt = 0; nt < 8; ++nt) {
            short8 bfr[4];
#pragma unroll
            for (int ko = 0; ko < 4; ++ko) {
                int n = nt * 16 + lr;
                int k = ko * 32 + lg * 8;
                bfr[ko] = *(const short8*)&WT[n * 128 + k];
            }
#pragma unroll
            for (int mt = 0; mt < 2; ++mt)
#pragma unroll
                for (int ko = 0; ko < 4; ++ko)
                    acc[mt][nt] = __builtin_amdgcn_mfma_f32_16x16x32_bf16(
                        afrag[mt][ko], bfr[ko], acc[mt][nt], 0, 0, 0);
        }

        float bcol[8];
#pragma unroll
        for (int nt = 0; nt < 8; ++nt) bcol[nt] = bm[m][nt * 16 + lr];

        unsigned short* O = (m == 0) ? QVb : (m == 1) ? Kb : (QVb + 128);
        const size_t strd = (m == 1) ? 128 : 256;
#pragma unroll
        for (int mt = 0; mt < 2; ++mt)
#pragma unroll
            for (int i = 0; i < 4; ++i) {
                int node = base + w * 32 + mt * 16 + 4 * lg + i;
                if (node < N) {
#pragma unroll
                    for (int nt = 0; nt < 8; ++nt)
                        O[(size_t)node * strd + nt * 16 + lr] =
                            f2bf(acc[mt][nt][i] + bcol[nt]);
                }
            }
    }
}

// ---------------------------------------------------------------------------
// Kernel 2: dst histogram.
// ---------------------------------------------------------------------------
__global__ __launch_bounds__(256) void hist_kernel(
    const int* __restrict__ dst, int E, unsigned* __restrict__ cnt)
{
    for (int e = blockIdx.x * blockDim.x + threadIdx.x; e < E;
         e += gridDim.x * blockDim.x)
        atomicAdd(&cnt[dst[e]], 1u);
}

// ---------------------------------------------------------------------------
// Kernel 3a: per-chunk exclusive scan (1024 elements/block) + block totals.
// ---------------------------------------------------------------------------
__global__ __launch_bounds__(1024) void scan1_kernel(
    const unsigned* __restrict__ cnt, unsigned* __restrict__ off,
    unsigned* __restrict__ bsum, int N)
{
    __shared__ unsigned sh[1024];
    const int t = threadIdx.x;
    const int gid = blockIdx.x * 1024 + t;
    unsigned v = (gid < N) ? cnt[gid] : 0u;
    sh[t] = v;
    __syncthreads();
#pragma unroll
    for (int d = 1; d < 1024; d <<= 1) {
        unsigned u = (t >= d) ? sh[t - d] : 0u;
        __syncthreads();
        sh[t] += u;
        __syncthreads();
    }
    if (gid < N) off[gid] = sh[t] - v;
    if (t == 1023) bsum[blockIdx.x] = sh[1023];
}

// ---------------------------------------------------------------------------
// Kernel 3b: scan block totals (single block); off[N] = total.
// ---------------------------------------------------------------------------
__global__ __launch_bounds__(1024) void scan2_kernel(
    const unsigned* __restrict__ bsum, unsigned* __restrict__ bbase,
    unsigned* __restrict__ off, int nb, int N)
{
    __shared__ unsigned sh[1024];
    const int t = threadIdx.x;
    unsigned v = (t < nb) ? bsum[t] : 0u;
    sh[t] = v;
    __syncthreads();
#pragma unroll
    for (int d = 1; d < 1024; d <<= 1) {
        unsigned u = (t >= d) ? sh[t - d] : 0u;
        __syncthreads();
        sh[t] += u;
        __syncthreads();
    }
    if (t < nb) bbase[t] = sh[t] - v;
    if (t == 1023) off[N] = sh[1023];
}

// ---------------------------------------------------------------------------
// Kernel 3c: add chunk base; write cursor copy.
// ---------------------------------------------------------------------------
__global__ __launch_bounds__(1024) void scan3_kernel(
    unsigned* __restrict__ off, unsigned* __restrict__ cursor,
    const unsigned* __restrict__ bbase, int N)
{
    const int gid = blockIdx.x * 1024 + threadIdx.x;
    if (gid < N) {
        unsigned o = off[gid] + bbase[blockIdx.x];
        off[gid] = o;
        cursor[gid] = o;
    }
}

// ---------------------------------------------------------------------------
// Kernel 4: reorder edge sources into CSR order (4B records).
// ---------------------------------------------------------------------------
__global__ __launch_bounds__(256) void reorder_kernel(
    const int* __restrict__ ei, int E,
    unsigned* __restrict__ cursor, int* __restrict__ rec_src)
{
    for (int e = blockIdx.x * blockDim.x + threadIdx.x; e < E;
         e += gridDim.x * blockDim.x) {
        int s = ei[e];
        int t = ei[E + e];
        unsigned pos = atomicAdd(&cursor[t], 1u);
        rec_src[pos] = s;
    }
}

// ---------------------------------------------------------------------------
// Kernel 5: fused per-node attention: scores + exp + weighted V aggregation.
// One wave per dst node; 4 edge-slots x 16 lanes; unrolled x2 -> 8 edges in
// flight per wave. QV record = 512B (Q row ++ V row) -> one contiguous
// gather region per edge. aggb written UNNORMALIZED; per-head exp-sums go
// to 64 partial buckets (reduced in out_mfma).
// ---------------------------------------------------------------------------
__global__ __launch_bounds__(256) void node_attn_kernel(
    const unsigned short* __restrict__ QV, const unsigned short* __restrict__ Kb,
    const int* __restrict__ rec_src, const unsigned* __restrict__ off,
    unsigned short* __restrict__ aggb, float* __restrict__ partials, int N)
{
    const int node = blockIdx.x * 4 + (threadIdx.x >> 6);
    if (node >= N) return;
    const int lane = threadIdx.x & 63;
    const int g = lane >> 4;
    const int j = lane & 15;
    const float scale = 0.17677669529663687f;   // 1/sqrt(32)

    const unsigned lo = off[node], hi = off[node + 1];

    const uint4 kreg = *(const uint4*)&Kb[(size_t)node * 128 + j * 8];

    float acc[8] = {0.f, 0.f, 0.f, 0.f, 0.f, 0.f, 0.f, 0.f};
    float ls = 0.f;

    for (unsigned i = lo; i < hi; i += 8) {
        unsigned e0 = i + g, e1 = i + 4 + g;
        bool val0 = e0 < hi, val1 = e1 < hi;
        int s0 = rec_src[val0 ? e0 : lo];
        int s1 = rec_src[val1 ? e1 : lo];
        uint4 q0 = *(const uint4*)&QV[(size_t)s0 * 256 + j * 8];
        uint4 v0 = *(const uint4*)&QV[(size_t)s0 * 256 + 128 + j * 8];
        uint4 q1 = *(const uint4*)&QV[(size_t)s1 * 256 + j * 8];
        uint4 v1 = *(const uint4*)&QV[(size_t)s1 * 256 + 128 + j * 8];

        float p0 = 0.f;
        p0 = prod2(q0.x, kreg.x, p0);
        p0 = prod2(q0.y, kreg.y, p0);
        p0 = prod2(q0.z, kreg.z, p0);
        p0 = prod2(q0.w, kreg.w, p0);
        float p1 = 0.f;
        p1 = prod2(q1.x, kreg.x, p1);
        p1 = prod2(q1.y, kreg.y, p1);
        p1 = prod2(q1.z, kreg.z, p1);
        p1 = prod2(q1.w, kreg.w, p1);

        p0 += __shfl_xor(p0, 1);
        p1 += __shfl_xor(p1, 1);
        p0 += __shfl_xor(p0, 2);
        p1 += __shfl_xor(p1, 2);

        float sv0 = p0 * scale;
        sv0 = (sv0 >= 0.f) ? sv0 : 0.2f * sv0;     // LeakyReLU(0.2)
        float a0 = val0 ? __expf(sv0) : 0.f;       // global softmax: no max shift
        float sv1 = p1 * scale;
        sv1 = (sv1 >= 0.f) ? sv1 : 0.2f * sv1;
        float a1 = val1 ? __expf(sv1) : 0.f;
        if ((j & 3) == 0) ls += a0 + a1;

        acc[0] = fmaf(a0, bflo(v0.x), acc[0]);
        acc[1] = fmaf(a0, bfhi(v0.x), acc[1]);
        acc[2] = fmaf(a0, bflo(v0.y), acc[2]);
        acc[3] = fmaf(a0, bfhi(v0.y), acc[3]);
        acc[4] = fmaf(a0, bflo(v0.z), acc[4]);
        acc[5] = fmaf(a0, bfhi(v0.z), acc[5]);
        acc[6] = fmaf(a0, bflo(v0.w), acc[6]);
        acc[7] = fmaf(a0, bfhi(v0.w), acc[7]);

        acc[0] = fmaf(a1, bflo(v1.x), acc[0]);
        acc[1] = fmaf(a1, bfhi(v1.x), acc[1]);
        acc[2] = fmaf(a1, bflo(v1.y), acc[2]);
        acc[3] = fmaf(a1, bfhi(v1.y), acc[3]);
        acc[4] = fmaf(a1, bflo(v1.z), acc[4]);
        acc[5] = fmaf(a1, bfhi(v1.z), acc[5]);
        acc[6] = fmaf(a1, bflo(v1.w), acc[6]);
        acc[7] = fmaf(a1, bfhi(v1.w), acc[7]);
    }

#pragma unroll
    for (int k = 0; k < 8; ++k) {
        acc[k] += __shfl_xor(acc[k], 16);
        acc[k] += __shfl_xor(acc[k], 32);
    }
    ls += __shfl_xor(ls, 16);
    ls += __shfl_xor(ls, 32);

    if (lane < 16) {
        uint4 o;
        o.x = packbf2(acc[0], acc[1]);
        o.y = packbf2(acc[2], acc[3]);
        o.z = packbf2(acc[4], acc[5]);
        o.w = packbf2(acc[6], acc[7]);
        *(uint4*)&aggb[(size_t)node * 128 + j * 8] = o;
        if ((j & 3) == 0)
            atomicAdd(&partials[(blockIdx.x & 63) * 4 + (j >> 2)], ls);
    }
}

// ---------------------------------------------------------------------------
// Kernel 6: h = (aggb * inv_sum) @ Wo + bo via MFMA; y = x + h; LayerNorm.
// ---------------------------------------------------------------------------
__global__ __launch_bounds__(256) void out_mfma(
    const float* __restrict__ x, const unsigned short* __restrict__ aggb,
    const unsigned short* __restrict__ WoT,
    const float* __restrict__ bo, const float* __restrict__ gamma,
    const float* __restrict__ beta, const float* __restrict__ partials,
    float* __restrict__ out, int N)
{
    __shared__ unsigned short as_[128 * 128];   // 32 KB, swizzled
    __shared__ float invs[4];
    const int tid  = threadIdx.x;
    const int base = blockIdx.x * 128;

    if (tid < 64) {
        float4 ps = ((const float4*)partials)[tid];
#pragma unroll
        for (int m = 1; m < 64; m <<= 1) {
            ps.x += __shfl_xor(ps.x, m);
            ps.y += __shfl_xor(ps.y, m);
            ps.z += __shfl_xor(ps.z, m);
            ps.w += __shfl_xor(ps.w, m);
        }
        if (tid == 0) {
            invs[0] = 1.f / ps.x; invs[1] = 1.f / ps.y;
            invs[2] = 1.f / ps.z; invs[3] = 1.f / ps.w;
        }
    }
    __syncthreads();

    for (int g = tid; g < 2048; g += 256) {
        int row = g >> 4, c = g & 15;
        int node = base + row;
        uint4 v = (node < N) ? *(const uint4*)&aggb[(size_t)node * 128 + c * 8]
                             : make_uint4(0u, 0u, 0u, 0u);
        float iv = invs[c >> 2];   // chunk c covers dims [8c,8c+8) -> head c>>2
        uint4 pk;
        pk.x = packbf2(bflo(v.x) * iv, bfhi(v.x) * iv);
        pk.y = packbf2(bflo(v.y) * iv, bfhi(v.y) * iv);
        pk.z = packbf2(bflo(v.z) * iv, bfhi(v.z) * iv);
        pk.w = packbf2(bflo(v.w) * iv, bfhi(v.w) * iv);
        int sc = c ^ (row & 15);
        *(uint4*)&as_[row * 128 + sc * 8] = pk;
    }
    __syncthreads();

    const int lane = tid & 63;
    const int w    = tid >> 6;
    const int lr   = lane & 15;
    const int lg   = lane >> 4;

    short8 afrag[2][4];
#pragma unroll
    for (int mt = 0; mt < 2; ++mt)
#pragma unroll
        for (int ko = 0; ko < 4; ++ko) {
            int row = w * 32 + mt * 16 + lr;
            int sc  = (ko * 4 + lg) ^ lr;
            afrag[mt][ko] = *(const short8*)&as_[row * 128 + sc * 8];
        }

    f32x4 acc[2][8];
#pragma unroll
    for (int mt = 0; mt < 2; ++mt)
#pragma unroll
        for (int nt = 0; nt < 8; ++nt)
            acc[mt][nt] = (f32x4){0.f, 0.f, 0.f, 0.f};

#pragma unroll
    for (int nt = 0; nt < 8; ++nt) {
        short8 bfr[4];
#pragma unroll
        for (int ko = 0; ko < 4; ++ko) {
            int n = nt * 16 + lr;
            int k = ko * 32 + lg * 8;
            bfr[ko] = *(const short8*)&WoT[n * 128 + k];
        }
#pragma unroll
        for (int mt = 0; mt < 2; ++mt)
#pragma unroll
            for (int ko = 0; ko < 4; ++ko)
                acc[mt][nt] = __builtin_amdgcn_mfma_f32_16x16x32_bf16(
                    afrag[mt][ko], bfr[ko], acc[mt][nt], 0, 0, 0);
    }

    float bo8[8], gg8[8], bb8[8];
#pragma unroll
    for (int nt = 0; nt < 8; ++nt) {
        bo8[nt] = bo[nt * 16 + lr];
        gg8[nt] = gamma[nt * 16 + lr];
        bb8[nt] = beta[nt * 16 + lr];
    }

#pragma unroll
    for (int mt = 0; mt < 2; ++mt)
#pragma unroll
        for (int i = 0; i < 4; ++i) {
            int node = base + w * 32 + mt * 16 + 4 * lg + i;
            if (node >= N) continue;
            float y8[8];
            float ps = 0.f;
#pragma unroll
            for (int nt = 0; nt < 8; ++nt) {
                float y = acc[mt][nt][i] + bo8[nt]
                        + x[(size_t)node * 128 + nt * 16 + lr];
                y8[nt] = y;
                ps += y;
            }
#pragma unroll
            for (int m = 1; m < 16; m <<= 1) ps += __shfl_xor(ps, m);
            float mu = ps * (1.0f / 128.0f);

            float pv = 0.f;
#pragma unroll
            for (int nt = 0; nt < 8; ++nt) {
                float d = y8[nt] - mu;
                pv = fmaf(d, d, pv);
            }
#pragma unroll
            for (int m = 1; m < 16; m <<= 1) pv += __shfl_xor(pv, m);
            float rstd = rsqrtf(pv * (1.0f / 128.0f) + LN_EPS);

#pragma unroll
            for (int nt = 0; nt < 8; ++nt)
                out[(size_t)node * 128 + nt * 16 + lr] =
                    (y8[nt] - mu) * rstd * gg8[nt] + bb8[nt];
        }
}

// ---------------------------------------------------------------------------
extern "C" void kernel_launch(void* const* d_in, const int* in_sizes, int n_in,
                              void* d_out, int out_size, void* d_ws, size_t ws_size,
                              hipStream_t stream)
{
    const float* x     = (const float*)d_in[0];
    const int*   ei    = (const int*)d_in[1];
    const float* Wq    = (const float*)d_in[2];
    const float* bq    = (const float*)d_in[3];
    const float* Wk    = (const float*)d_in[4];
    const float* bk    = (const float*)d_in[5];
    const float* Wv    = (const float*)d_in[6];
    const float* bv    = (const float*)d_in[7];
    const float* Wo    = (const float*)d_in[8];
    const float* bo    = (const float*)d_in[9];
    const float* gamma = (const float*)d_in[10];
    const float* beta  = (const float*)d_in[11];
    float* out = (float*)d_out;

    const int N = in_sizes[0] / 128;
    const int E = in_sizes[1] / 2;

    // workspace layout
    char* p = (char*)d_ws;
    unsigned short* QVb  = (unsigned short*)p; p += (size_t)N * 256 * 2;  // Q||V interleaved
    unsigned short* Kb   = (unsigned short*)p; p += (size_t)N * 128 * 2;
    unsigned short* aggb = (unsigned short*)p; p += (size_t)N * 128 * 2;
    int* rec_src = (int*)p; p += (size_t)E * 4;
    unsigned short* WqT = (unsigned short*)p; p += 16384 * 2;
    unsigned short* WkT = (unsigned short*)p; p += 16384 * 2;
    unsigned short* WvT = (unsigned short*)p; p += 16384 * 2;
    unsigned short* WoT = (unsigned short*)p; p += 16384 * 2;
    float*    partials = (float*)p;  p += 256 * 4;          // 64 buckets x 4 heads
    unsigned* cnt      = (unsigned*)p; p += (size_t)N * 4;
    unsigned* off      = (unsigned*)p; p += (size_t)(N + 1) * 4;
    unsigned* cursor   = (unsigned*)p; p += (size_t)N * 4;
    unsigned* bsum     = (unsigned*)p; p += 1024 * 4;
    unsigned* bbase    = (unsigned*)p;

    // zero partials + cnt (contiguous)
    hipMemsetAsync(partials, 0, (size_t)(256 + N) * sizeof(unsigned), stream);

    const int nb  = (N + 127) / 128;
    const int nsc = (N + 1023) / 1024;
    prep_kernel<<<4, 256, 0, stream>>>(Wq, Wk, Wv, Wo, WqT, WkT, WvT, WoT);
    qkv_mfma<<<nb, 256, 0, stream>>>(x, WqT, WkT, WvT, bq, bk, bv, QVb, Kb, N);
    hist_kernel<<<1024, 256, 0, stream>>>(ei + E, E, cnt);
    scan1_kernel<<<nsc, 1024, 0, stream>>>(cnt, off, bsum, N);
    scan2_kernel<<<1, 1024, 0, stream>>>(bsum, bbase, off, nsc, N);
    scan3_kernel<<<nsc, 1024, 0, stream>>>(off, cursor, bbase, N);
    reorder_kernel<<<1024, 256, 0, stream>>>(ei, E, cursor, rec_src);
    node_attn_kernel<<<(N + 3) / 4, 256, 0, stream>>>(QVb, Kb, rec_src, off,
                                                      aggb, partials, N);
    out_mfma<<<nb, 256, 0, stream>>>(x, aggb, WoT, bo, gamma, beta, partials,
                                     out, N);
}

// Round 8
// 253.642 us; speedup vs baseline: 6.6284x; 1.0402x over previous
//
#include <hip/hip_runtime.h>
#include <math.h>

#define LN_EPS 1e-5f

typedef short short8 __attribute__((ext_vector_type(8)));
typedef float f32x4  __attribute__((ext_vector_type(4)));
typedef float f32x2  __attribute__((ext_vector_type(2)));

// ---- bf16 helpers (bit-level; RNE on encode) ----
__device__ __forceinline__ unsigned short f2bf(float f) {
    unsigned u = __float_as_uint(f);
    u += 0x7FFFu + ((u >> 16) & 1u);
    return (unsigned short)(u >> 16);
}
__device__ __forceinline__ unsigned packbf2(float lo, float hi) {
    return (unsigned)f2bf(lo) | ((unsigned)f2bf(hi) << 16);
}
__device__ __forceinline__ float bflo(unsigned u) { return __uint_as_float(u << 16); }
__device__ __forceinline__ float bfhi(unsigned u) { return __uint_as_float(u & 0xFFFF0000u); }

// ---- fp8 e4m3 helpers (HW cvt; word selector must be a LITERAL constant) ----
__device__ __forceinline__ f32x2 fp8lo(unsigned u) {
    return __builtin_amdgcn_cvt_pk_f32_fp8((int)u, false);
}
__device__ __forceinline__ f32x2 fp8hi(unsigned u) {
    return __builtin_amdgcn_cvt_pk_f32_fp8((int)u, true);
}
__device__ __forceinline__ unsigned char f2fp8(float f) {
    return (unsigned char)(__builtin_amdgcn_cvt_pk_fp8_f32(f, f, 0, false) & 0xFF);
}

// ---------------------------------------------------------------------------
// Kernel 0: transpose weights to bf16 W^T  (WT[n][k] = W[k][n]).
// ---------------------------------------------------------------------------
__global__ __launch_bounds__(256) void prep_kernel(
    const float* __restrict__ W0, const float* __restrict__ W1,
    const float* __restrict__ W2, const float* __restrict__ W3,
    unsigned short* __restrict__ T0, unsigned short* __restrict__ T1,
    unsigned short* __restrict__ T2, unsigned short* __restrict__ T3)
{
    const float* W = (blockIdx.x == 0) ? W0 : (blockIdx.x == 1) ? W1
                   : (blockIdx.x == 2) ? W2 : W3;
    unsigned short* T = (blockIdx.x == 0) ? T0 : (blockIdx.x == 1) ? T1
                      : (blockIdx.x == 2) ? T2 : T3;
    const int t = threadIdx.x;
    const int n = (t & 31) * 4;
    for (int k = t >> 5; k < 128; k += 8) {
        float4 w = ((const float4*)W)[k * 32 + (t & 31)];
        T[(n + 0) * 128 + k] = f2bf(w.x);
        T[(n + 1) * 128 + k] = f2bf(w.y);
        T[(n + 2) * 128 + k] = f2bf(w.z);
        T[(n + 3) * 128 + k] = f2bf(w.w);
    }
}

// ---------------------------------------------------------------------------
// Kernel 1: Q/K/V GEMM via bf16 MFMA + fused dst histogram.
// Outputs fp8 e4m3: QV8 record per node = 16 chunks of 16B, chunk j =
// [Q dims 8j..8j+7 | V dims 8j..8j+7].  K8 = [node][128] fp8.
// ---------------------------------------------------------------------------
__global__ __launch_bounds__(256) void qkv_mfma(
    const float* __restrict__ x,
    const unsigned short* __restrict__ WqT, const unsigned short* __restrict__ WkT,
    const unsigned short* __restrict__ WvT,
    const float* __restrict__ bq, const float* __restrict__ bk,
    const float* __restrict__ bv,
    unsigned char* __restrict__ QV8, unsigned char* __restrict__ K8,
    const int* __restrict__ dst, int E, unsigned* __restrict__ cnt, int N)
{
    __shared__ unsigned short xs[128 * 128];   // 32 KB, swizzled
    const int tid  = threadIdx.x;
    const int base = blockIdx.x * 128;

    // fused dst histogram (independent of GEMM work)
    for (int e = blockIdx.x * 256 + tid; e < E; e += gridDim.x * 256)
        atomicAdd(&cnt[dst[e]], 1u);

    for (int g = tid; g < 2048; g += 256) {
        int row = g >> 4, c = g & 15;
        int node = base + row;
        float4 a, b;
        if (node < N) {
            a = ((const float4*)x)[(size_t)node * 32 + c * 2];
            b = ((const float4*)x)[(size_t)node * 32 + c * 2 + 1];
        } else {
            a = make_float4(0.f, 0.f, 0.f, 0.f);
            b = a;
        }
        uint4 pk;
        pk.x = packbf2(a.x, a.y);
        pk.y = packbf2(a.z, a.w);
        pk.z = packbf2(b.x, b.y);
        pk.w = packbf2(b.z, b.w);
        int sc = c ^ (row & 15);
        *(uint4*)&xs[row * 128 + sc * 8] = pk;
    }
    __syncthreads();

    const int lane = tid & 63;
    const int w    = tid >> 6;
    const int lr   = lane & 15;
    const int lg   = lane >> 4;

    short8 afrag[2][4];
#pragma unroll
    for (int mt = 0; mt < 2; ++mt)
#pragma unroll
        for (int ko = 0; ko < 4; ++ko) {
            int row = w * 32 + mt * 16 + lr;
            int sc  = (ko * 4 + lg) ^ lr;
            afrag[mt][ko] = *(const short8*)&xs[row * 128 + sc * 8];
        }

    const unsigned short* WTm[3] = {WqT, WkT, WvT};
    const float*          bm[3]  = {bq, bk, bv};

    for (int m = 0; m < 3; ++m) {
        const unsigned short* WT = WTm[m];
        f32x4 acc[2][8];
#pragma unroll
        for (int mt = 0; mt < 2; ++mt)
#pragma unroll
            for (int nt = 0; nt < 8; ++nt)
                acc[mt][nt] = (f32x4){0.f, 0.f, 0.f, 0.f};

#pragma unroll
        for (int nt = 0; nt < 8; ++nt) {
            short8 bfr[4];
#pragma unroll
            for (int ko = 0; ko < 4; ++ko) {
                int n = nt * 16 + lr;
                int k = ko * 32 + lg * 8;
                bfr[ko] = *(const short8*)&WT[n * 128 + k];
            }
#pragma unroll
            for (int mt = 0; mt < 2; ++mt)
#pragma unroll
                for (int ko = 0; ko < 4; ++ko)
                    acc[mt][nt] = __builtin_amdgcn_mfma_f32_16x16x32_bf16(
                        afrag[mt][ko], bfr[ko], acc[mt][nt], 0, 0, 0);
        }

        float bcol[8];
#pragma unroll
        for (int nt = 0; nt < 8; ++nt) bcol[nt] = bm[m][nt * 16 + lr];

#pragma unroll
        for (int mt = 0; mt < 2; ++mt)
#pragma unroll
            for (int i = 0; i < 4; ++i) {
                int node = base + w * 32 + mt * 16 + 4 * lg + i;
                if (node >= N) continue;
                if (m == 1) {
#pragma unroll
                    for (int nt = 0; nt < 8; ++nt)
                        K8[(size_t)node * 128 + nt * 16 + lr] =
                            f2fp8(acc[mt][nt][i] + bcol[nt]);
                } else {
                    // col c = nt*16+lr -> chunk j=c>>3, byte c&7; Q at +0, V at +8
                    const size_t rb = (size_t)node * 256 + (m == 0 ? 0 : 8)
                                    + (lr >> 3) * 16 + (lr & 7);
#pragma unroll
                    for (int nt = 0; nt < 8; ++nt)
                        QV8[rb + nt * 32] = f2fp8(acc[mt][nt][i] + bcol[nt]);
                }
            }
    }
}

// ---------------------------------------------------------------------------
// Kernel 3a: per-chunk exclusive scan (1024 elements/block) + block totals.
// ---------------------------------------------------------------------------
__global__ __launch_bounds__(1024) void scan1_kernel(
    const unsigned* __restrict__ cnt, unsigned* __restrict__ off,
    unsigned* __restrict__ bsum, int N)
{
    __shared__ unsigned sh[1024];
    const int t = threadIdx.x;
    const int gid = blockIdx.x * 1024 + t;
    unsigned v = (gid < N) ? cnt[gid] : 0u;
    sh[t] = v;
    __syncthreads();
#pragma unroll
    for (int d = 1; d < 1024; d <<= 1) {
        unsigned u = (t >= d) ? sh[t - d] : 0u;
        __syncthreads();
        sh[t] += u;
        __syncthreads();
    }
    if (gid < N) off[gid] = sh[t] - v;
    if (t == 1023) bsum[blockIdx.x] = sh[1023];
}

// ---------------------------------------------------------------------------
// Kernel 3b: scan block totals (single block); off[N] = total.
// ---------------------------------------------------------------------------
__global__ __launch_bounds__(1024) void scan2_kernel(
    const unsigned* __restrict__ bsum, unsigned* __restrict__ bbase,
    unsigned* __restrict__ off, int nb, int N)
{
    __shared__ unsigned sh[1024];
    const int t = threadIdx.x;
    unsigned v = (t < nb) ? bsum[t] : 0u;
    sh[t] = v;
    __syncthreads();
#pragma unroll
    for (int d = 1; d < 1024; d <<= 1) {
        unsigned u = (t >= d) ? sh[t - d] : 0u;
        __syncthreads();
        sh[t] += u;
        __syncthreads();
    }
    if (t < nb) bbase[t] = sh[t] - v;
    if (t == 1023) off[N] = sh[1023];
}

// ---------------------------------------------------------------------------
// Kernel 3c: add chunk base; write cursor copy.
// ---------------------------------------------------------------------------
__global__ __launch_bounds__(1024) void scan3_kernel(
    unsigned* __restrict__ off, unsigned* __restrict__ cursor,
    const unsigned* __restrict__ bbase, int N)
{
    const int gid = blockIdx.x * 1024 + threadIdx.x;
    if (gid < N) {
        unsigned o = off[gid] + bbase[blockIdx.x];
        off[gid] = o;
        cursor[gid] = o;
    }
}

// ---------------------------------------------------------------------------
// Kernel 4: reorder edge sources into CSR order (4B records).
// ---------------------------------------------------------------------------
__global__ __launch_bounds__(256) void reorder_kernel(
    const int* __restrict__ ei, int E,
    unsigned* __restrict__ cursor, int* __restrict__ rec_src)
{
    for (int e = blockIdx.x * blockDim.x + threadIdx.x; e < E;
         e += gridDim.x * blockDim.x) {
        int s = ei[e];
        int t = ei[E + e];
        unsigned pos = atomicAdd(&cursor[t], 1u);
        rec_src[pos] = s;
    }
}

// ---------------------------------------------------------------------------
// Kernel 5: fused per-node attention (fp8 gathers): scores + exp + weighted
// V aggregation.  One wave per dst node; 4 edge-slots x 16 lanes, unrolled
// x2 (8 edges in flight).  Per edge per lane: ONE 16B load covering both
// the Q and V sub-chunks.  aggb (bf16) written UNNORMALIZED; per-head
// exp-sums -> 64 partial buckets (reduced in out_mfma).
// ---------------------------------------------------------------------------
__global__ __launch_bounds__(256) void node_attn_kernel(
    const unsigned char* __restrict__ QV8, const unsigned char* __restrict__ K8,
    const int* __restrict__ rec_src, const unsigned* __restrict__ off,
    unsigned short* __restrict__ aggb, float* __restrict__ partials, int N)
{
    const int node = blockIdx.x * 4 + (threadIdx.x >> 6);
    if (node >= N) return;
    const int lane = threadIdx.x & 63;
    const int g = lane >> 4;
    const int j = lane & 15;
    const float scale = 0.17677669529663687f;   // 1/sqrt(32)

    const unsigned lo = off[node], hi = off[node + 1];

    // K[node] dims [8j, 8j+8) decoded to registers
    const uint2 kw = *(const uint2*)&K8[(size_t)node * 128 + j * 8];
    const f32x2 ka = fp8lo(kw.x), kb = fp8hi(kw.x);
    const f32x2 kc = fp8lo(kw.y), kd = fp8hi(kw.y);

    float acc[8] = {0.f, 0.f, 0.f, 0.f, 0.f, 0.f, 0.f, 0.f};
    float ls = 0.f;

    for (unsigned i = lo; i < hi; i += 8) {
        unsigned e0 = i + g, e1 = i + 4 + g;
        bool val0 = e0 < hi, val1 = e1 < hi;
        int s0 = rec_src[val0 ? e0 : lo];
        int s1 = rec_src[val1 ? e1 : lo];
        uint4 r0 = *(const uint4*)&QV8[(size_t)s0 * 256 + j * 16];
        uint4 r1 = *(const uint4*)&QV8[(size_t)s1 * 256 + j * 16];

        f32x2 qa0 = fp8lo(r0.x), qb0 = fp8hi(r0.x);
        f32x2 qc0 = fp8lo(r0.y), qd0 = fp8hi(r0.y);
        f32x2 qa1 = fp8lo(r1.x), qb1 = fp8hi(r1.x);
        f32x2 qc1 = fp8lo(r1.y), qd1 = fp8hi(r1.y);

        float p0 = qa0.x * ka.x + qa0.y * ka.y + qb0.x * kb.x + qb0.y * kb.y
                 + qc0.x * kc.x + qc0.y * kc.y + qd0.x * kd.x + qd0.y * kd.y;
        float p1 = qa1.x * ka.x + qa1.y * ka.y + qb1.x * kb.x + qb1.y * kb.y
                 + qc1.x * kc.x + qc1.y * kc.y + qd1.x * kd.x + qd1.y * kd.y;

        p0 += __shfl_xor(p0, 1);
        p1 += __shfl_xor(p1, 1);
        p0 += __shfl_xor(p0, 2);
        p1 += __shfl_xor(p1, 2);   // full 32-dim head dot in each 4-lane group

        float sv0 = p0 * scale;
        sv0 = (sv0 >= 0.f) ? sv0 : 0.2f * sv0;     // LeakyReLU(0.2)
        float a0 = val0 ? __expf(sv0) : 0.f;       // global softmax: no max shift
        float sv1 = p1 * scale;
        sv1 = (sv1 >= 0.f) ? sv1 : 0.2f * sv1;
        float a1 = val1 ? __expf(sv1) : 0.f;
        if ((j & 3) == 0) ls += a0 + a1;

        f32x2 va0 = fp8lo(r0.z), vb0 = fp8hi(r0.z);
        f32x2 vc0 = fp8lo(r0.w), vd0 = fp8hi(r0.w);
        f32x2 va1 = fp8lo(r1.z), vb1 = fp8hi(r1.z);
        f32x2 vc1 = fp8lo(r1.w), vd1 = fp8hi(r1.w);

        acc[0] = fmaf(a0, va0.x, acc[0]);
        acc[1] = fmaf(a0, va0.y, acc[1]);
        acc[2] = fmaf(a0, vb0.x, acc[2]);
        acc[3] = fmaf(a0, vb0.y, acc[3]);
        acc[4] = fmaf(a0, vc0.x, acc[4]);
        acc[5] = fmaf(a0, vc0.y, acc[5]);
        acc[6] = fmaf(a0, vd0.x, acc[6]);
        acc[7] = fmaf(a0, vd0.y, acc[7]);

        acc[0] = fmaf(a1, va1.x, acc[0]);
        acc[1] = fmaf(a1, va1.y, acc[1]);
        acc[2] = fmaf(a1, vb1.x, acc[2]);
        acc[3] = fmaf(a1, vb1.y, acc[3]);
        acc[4] = fmaf(a1, vc1.x, acc[4]);
        acc[5] = fmaf(a1, vc1.y, acc[5]);
        acc[6] = fmaf(a1, vd1.x, acc[6]);
        acc[7] = fmaf(a1, vd1.y, acc[7]);
    }

#pragma unroll
    for (int k = 0; k < 8; ++k) {
        acc[k] += __shfl_xor(acc[k], 16);
        acc[k] += __shfl_xor(acc[k], 32);
    }
    ls += __shfl_xor(ls, 16);
    ls += __shfl_xor(ls, 32);

    if (lane < 16) {
        uint4 o;
        o.x = packbf2(acc[0], acc[1]);
        o.y = packbf2(acc[2], acc[3]);
        o.z = packbf2(acc[4], acc[5]);
        o.w = packbf2(acc[6], acc[7]);
        *(uint4*)&aggb[(size_t)node * 128 + j * 8] = o;
        if ((j & 3) == 0)
            atomicAdd(&partials[(blockIdx.x & 63) * 4 + (j >> 2)], ls);
    }
}

// ---------------------------------------------------------------------------
// Kernel 6: h = (aggb * inv_sum) @ Wo + bo via MFMA; y = x + h; LayerNorm.
// ---------------------------------------------------------------------------
__global__ __launch_bounds__(256) void out_mfma(
    const float* __restrict__ x, const unsigned short* __restrict__ aggb,
    const unsigned short* __restrict__ WoT,
    const float* __restrict__ bo, const float* __restrict__ gamma,
    const float* __restrict__ beta, const float* __restrict__ partials,
    float* __restrict__ out, int N)
{
    __shared__ unsigned short as_[128 * 128];   // 32 KB, swizzled
    __shared__ float invs[4];
    const int tid  = threadIdx.x;
    const int base = blockIdx.x * 128;

    if (tid < 64) {
        float4 ps = ((const float4*)partials)[tid];
#pragma unroll
        for (int m = 1; m < 64; m <<= 1) {
            ps.x += __shfl_xor(ps.x, m);
            ps.y += __shfl_xor(ps.y, m);
            ps.z += __shfl_xor(ps.z, m);
            ps.w += __shfl_xor(ps.w, m);
        }
        if (tid == 0) {
            invs[0] = 1.f / ps.x; invs[1] = 1.f / ps.y;
            invs[2] = 1.f / ps.z; invs[3] = 1.f / ps.w;
        }
    }
    __syncthreads();

    for (int g = tid; g < 2048; g += 256) {
        int row = g >> 4, c = g & 15;
        int node = base + row;
        uint4 v = (node < N) ? *(const uint4*)&aggb[(size_t)node * 128 + c * 8]
                             : make_uint4(0u, 0u, 0u, 0u);
        float iv = invs[c >> 2];   // chunk c covers dims [8c,8c+8) -> head c>>2
        uint4 pk;
        pk.x = packbf2(bflo(v.x) * iv, bfhi(v.x) * iv);
        pk.y = packbf2(bflo(v.y) * iv, bfhi(v.y) * iv);
        pk.z = packbf2(bflo(v.z) * iv, bfhi(v.z) * iv);
        pk.w = packbf2(bflo(v.w) * iv, bfhi(v.w) * iv);
        int sc = c ^ (row & 15);
        *(uint4*)&as_[row * 128 + sc * 8] = pk;
    }
    __syncthreads();

    const int lane = tid & 63;
    const int w    = tid >> 6;
    const int lr   = lane & 15;
    const int lg   = lane >> 4;

    short8 afrag[2][4];
#pragma unroll
    for (int mt = 0; mt < 2; ++mt)
#pragma unroll
        for (int ko = 0; ko < 4; ++ko) {
            int row = w * 32 + mt * 16 + lr;
            int sc  = (ko * 4 + lg) ^ lr;
            afrag[mt][ko] = *(const short8*)&as_[row * 128 + sc * 8];
        }

    f32x4 acc[2][8];
#pragma unroll
    for (int mt = 0; mt < 2; ++mt)
#pragma unroll
        for (int nt = 0; nt < 8; ++nt)
            acc[mt][nt] = (f32x4){0.f, 0.f, 0.f, 0.f};

#pragma unroll
    for (int nt = 0; nt < 8; ++nt) {
        short8 bfr[4];
#pragma unroll
        for (int ko = 0; ko < 4; ++ko) {
            int n = nt * 16 + lr;
            int k = ko * 32 + lg * 8;
            bfr[ko] = *(const short8*)&WoT[n * 128 + k];
        }
#pragma unroll
        for (int mt = 0; mt < 2; ++mt)
#pragma unroll
            for (int ko = 0; ko < 4; ++ko)
                acc[mt][nt] = __builtin_amdgcn_mfma_f32_16x16x32_bf16(
                    afrag[mt][ko], bfr[ko], acc[mt][nt], 0, 0, 0);
    }

    float bo8[8], gg8[8], bb8[8];
#pragma unroll
    for (int nt = 0; nt < 8; ++nt) {
        bo8[nt] = bo[nt * 16 + lr];
        gg8[nt] = gamma[nt * 16 + lr];
        bb8[nt] = beta[nt * 16 + lr];
    }

#pragma unroll
    for (int mt = 0; mt < 2; ++mt)
#pragma unroll
        for (int i = 0; i < 4; ++i) {
            int node = base + w * 32 + mt * 16 + 4 * lg + i;
            if (node >= N) continue;
            float y8[8];
            float ps = 0.f;
#pragma unroll
            for (int nt = 0; nt < 8; ++nt) {
                float y = acc[mt][nt][i] + bo8[nt]
                        + x[(size_t)node * 128 + nt * 16 + lr];
                y8[nt] = y;
                ps += y;
            }
#pragma unroll
            for (int m = 1; m < 16; m <<= 1) ps += __shfl_xor(ps, m);
            float mu = ps * (1.0f / 128.0f);

            float pv = 0.f;
#pragma unroll
            for (int nt = 0; nt < 8; ++nt) {
                float d = y8[nt] - mu;
                pv = fmaf(d, d, pv);
            }
#pragma unroll
            for (int m = 1; m < 16; m <<= 1) pv += __shfl_xor(pv, m);
            float rstd = rsqrtf(pv * (1.0f / 128.0f) + LN_EPS);

#pragma unroll
            for (int nt = 0; nt < 8; ++nt)
                out[(size_t)node * 128 + nt * 16 + lr] =
                    (y8[nt] - mu) * rstd * gg8[nt] + bb8[nt];
        }
}

// ---------------------------------------------------------------------------
extern "C" void kernel_launch(void* const* d_in, const int* in_sizes, int n_in,
                              void* d_out, int out_size, void* d_ws, size_t ws_size,
                              hipStream_t stream)
{
    const float* x     = (const float*)d_in[0];
    const int*   ei    = (const int*)d_in[1];
    const float* Wq    = (const float*)d_in[2];
    const float* bq    = (const float*)d_in[3];
    const float* Wk    = (const float*)d_in[4];
    const float* bk    = (const float*)d_in[5];
    const float* Wv    = (const float*)d_in[6];
    const float* bv    = (const float*)d_in[7];
    const float* Wo    = (const float*)d_in[8];
    const float* bo    = (const float*)d_in[9];
    const float* gamma = (const float*)d_in[10];
    const float* beta  = (const float*)d_in[11];
    float* out = (float*)d_out;

    const int N = in_sizes[0] / 128;
    const int E = in_sizes[1] / 2;

    // workspace layout
    char* p = (char*)d_ws;
    unsigned char*  QV8  = (unsigned char*)p;  p += (size_t)N * 256;   // fp8 Q||V
    unsigned char*  K8   = (unsigned char*)p;  p += (size_t)N * 128;   // fp8 K
    unsigned short* aggb = (unsigned short*)p; p += (size_t)N * 128 * 2;
    int* rec_src = (int*)p; p += (size_t)E * 4;
    unsigned short* WqT = (unsigned short*)p; p += 16384 * 2;
    unsigned short* WkT = (unsigned short*)p; p += 16384 * 2;
    unsigned short* WvT = (unsigned short*)p; p += 16384 * 2;
    unsigned short* WoT = (unsigned short*)p; p += 16384 * 2;
    float*    partials = (float*)p;  p += 256 * 4;          // 64 buckets x 4 heads
    unsigned* cnt      = (unsigned*)p; p += (size_t)N * 4;
    unsigned* off      = (unsigned*)p; p += (size_t)(N + 1) * 4;
    unsigned* cursor   = (unsigned*)p; p += (size_t)N * 4;
    unsigned* bsum     = (unsigned*)p; p += 1024 * 4;
    unsigned* bbase    = (unsigned*)p;

    // zero partials + cnt (contiguous)
    (void)hipMemsetAsync(partials, 0, (size_t)(256 + N) * sizeof(unsigned), stream);

    const int nb  = (N + 127) / 128;
    const int nsc = (N + 1023) / 1024;
    prep_kernel<<<4, 256, 0, stream>>>(Wq, Wk, Wv, Wo, WqT, WkT, WvT, WoT);
    qkv_mfma<<<nb, 256, 0, stream>>>(x, WqT, WkT, WvT, bq, bk, bv,
                                     QV8, K8, ei + E, E, cnt, N);
    scan1_kernel<<<nsc, 1024, 0, stream>>>(cnt, off, bsum, N);
    scan2_kernel<<<1, 1024, 0, stream>>>(bsum, bbase, off, nsc, N);
    scan3_kernel<<<nsc, 1024, 0, stream>>>(off, cursor, bbase, N);
    reorder_kernel<<<1024, 256, 0, stream>>>(ei, E, cursor, rec_src);
    node_attn_kernel<<<(N + 3) / 4, 256, 0, stream>>>(QV8, K8, rec_src, off,
                                                      aggb, partials, N);
    out_mfma<<<nb, 256, 0, stream>>>(x, aggb, WoT, bo, gamma, beta, partials,
                                     out, N);
}